// Round 6
// baseline (510.436 us; speedup 1.0000x reference)
//
#include <hip/hip_runtime.h>
#include <hip/hip_bf16.h>
#include <stdint.h>

typedef __bf16 bf16x8 __attribute__((ext_vector_type(8)));
typedef float f32x4 __attribute__((ext_vector_type(4)));
typedef float f32x16 __attribute__((ext_vector_type(16)));
typedef uint32_t u32x4 __attribute__((ext_vector_type(4)));
typedef unsigned short u16;
typedef unsigned char u8;

typedef __attribute__((address_space(1))) void as1_void;
typedef __attribute__((address_space(3))) void as3_void;

#define BAR() __builtin_amdgcn_s_barrier()
#define VMCNT(n) asm volatile("s_waitcnt vmcnt(" #n ")" ::: "memory")
#define LGKM0() asm volatile("s_waitcnt lgkmcnt(0)" ::: "memory")

__device__ __forceinline__ u16 f2bf(float f) {
  uint32_t u = __float_as_uint(f);
  u += 0x7fffu + ((u >> 16) & 1u);
  return (u16)(u >> 16);
}

__device__ __forceinline__ uint32_t pk_fp8x4(float a, float b, float c, float d) {
  int v = __builtin_amdgcn_cvt_pk_fp8_f32(a, b, 0, false);
  v = __builtin_amdgcn_cvt_pk_fp8_f32(c, d, v, true);
  return (uint32_t)v;
}
__device__ __forceinline__ u8 f2fp8(float a) {
  return (u8)(__builtin_amdgcn_cvt_pk_fp8_f32(a, a, 0, false) & 0xff);
}

// epilogue segment descriptor (uniform per block)
struct Seg {
  const void* W;        // weight base (fp8 u8* or bf16 u16*), [1024,1024]
  const float* bias;    // [1024]
  u16* outb;            // mode 0/2 bf16 out
  float* outf;          // mode 1 fp32 out
  const float* res;     // mode 1 residual
  const float* gamma;   // mode 1 gamma
  int mode;             // 0 = bf16 rowmajor, 1 = fp32 res+gamma, 2 = Vt bf16
  int sk;               // mode2 shift
  float ascale;
};

// ---------------- fp32 -> fp8/bf16 weight convert (one dispatch) ----------------
__global__ __launch_bounds__(256) void cvt8_kernel(
    const float4* s0, const float4* s1, const float4* s2, const float4* s3,
    const float4* s4, const float4* s5, const float4* s6, const float4* s7,
    uint32_t* f0, uint32_t* f1, uint32_t* f2, uint32_t* f3,
    ushort4* h4, ushort4* h5, ushort4* h6, ushort4* h7) {
  int i = blockIdx.x * 256 + threadIdx.x;
  int y = blockIdx.y;
  if (y < 4) {
    const float4* s = (y == 0) ? s0 : (y == 1) ? s1 : (y == 2) ? s2 : s3;
    uint32_t* d = (y == 0) ? f0 : (y == 1) ? f1 : (y == 2) ? f2 : f3;
    float4 v = s[i];
    d[i] = pk_fp8x4(v.x, v.y, v.z, v.w);
  } else {
    const float4* s = (y == 4) ? s4 : (y == 5) ? s5 : (y == 6) ? s6 : s7;
    ushort4* d = (y == 4) ? h4 : (y == 5) ? h5 : (y == 6) ? h6 : h7;
    float4 v = s[i];
    ushort4 o;
    o.x = f2bf(v.x); o.y = f2bf(v.y); o.z = f2bf(v.z); o.w = f2bf(v.w);
    d[i] = o;
  }
}

// ---------------- layernorm fp32 -> (bf16 | fp8), D=1024 ----------------
template <int FP8>
__global__ __launch_bounds__(256) void ln_kernel(const float* __restrict__ x,
                                                 const float* __restrict__ g,
                                                 const float* __restrict__ b,
                                                 void* __restrict__ out) {
  int row = blockIdx.x;
  int t = threadIdx.x;
  const float4* xr = (const float4*)(x + (size_t)row * 1024);
  float4 v = xr[t];
  float s = v.x + v.y + v.z + v.w;
  float s2 = v.x * v.x + v.y * v.y + v.z * v.z + v.w * v.w;
#pragma unroll
  for (int off = 1; off < 64; off <<= 1) {
    s += __shfl_xor(s, off);
    s2 += __shfl_xor(s2, off);
  }
  __shared__ float red[8];
  int wv = t >> 6;
  if ((t & 63) == 0) { red[wv] = s; red[4 + wv] = s2; }
  __syncthreads();
  s = red[0] + red[1] + red[2] + red[3];
  s2 = red[4] + red[5] + red[6] + red[7];
  float mu = s * (1.0f / 1024.0f);
  float var = s2 * (1.0f / 1024.0f) - mu * mu;
  float rstd = rsqrtf(var + 1e-5f);
  const float4 gv = ((const float4*)g)[t];
  const float4 bv = ((const float4*)b)[t];
  float o0 = (v.x - mu) * rstd * gv.x + bv.x;
  float o1 = (v.y - mu) * rstd * gv.y + bv.y;
  float o2 = (v.z - mu) * rstd * gv.z + bv.z;
  float o3 = (v.w - mu) * rstd * gv.w + bv.w;
  if (FP8) {
    ((uint32_t*)out)[(size_t)row * 256 + t] = pk_fp8x4(o0, o1, o2, o3);
  } else {
    ushort4 o;
    o.x = f2bf(o0); o.y = f2bf(o1); o.z = f2bf(o2); o.w = f2bf(o3);
    ((ushort4*)out)[(size_t)row * 256 + t] = o;
  }
}

// ================= 128x128 bf16 GEMM (m97 structure), seg-fused epilogue =================
// grid (mtiles, ntiles); seg = blockIdx.y>>3 (8 n-tiles of 128 per 1024-col segment).
__global__ __launch_bounds__(256) void gemm128_kernel(
    const u16* __restrict__ A, Seg s0, Seg s1, Seg s2) {
  const int K = 1024;
  int m0 = blockIdx.x * 128;
  int yy = blockIdx.y;
  int si = yy >> 3;
  Seg seg = (si == 0) ? s0 : (si == 1) ? s1 : s2;
  int nl0 = (yy & 7) * 128;  // seg-local col base
  int t = threadIdx.x, lane = t & 63, wv = t >> 6;
  int wr = wv >> 1, wc = wv & 1;
  int lr = lane & 15, lk = (lane >> 4) * 8;
  __shared__ u16 As[128 * 32];
  __shared__ u16 Ws[128 * 32];
  const u16* Wb = (const u16*)seg.W;
  f32x4 acc[4][4] = {};
  for (int kt = 0; kt < K / 32; ++kt) {
#pragma unroll
    for (int i = 0; i < 2; ++i) {
      int c = i * 256 + t;
      int row = c >> 2, k8 = (c & 3) << 3;
      const u16* ga = A + (size_t)(m0 + row) * K + kt * 32 + k8;
      const u16* gw = Wb + (size_t)(nl0 + row) * K + kt * 32 + k8;
      __builtin_amdgcn_global_load_lds((const as1_void*)ga, (as3_void*)(As + c * 8), 16, 0, 0);
      __builtin_amdgcn_global_load_lds((const as1_void*)gw, (as3_void*)(Ws + c * 8), 16, 0, 0);
    }
    __syncthreads();
    bf16x8 af[4], wf[4];
#pragma unroll
    for (int m = 0; m < 4; ++m)
      af[m] = *(const bf16x8*)(As + (wr * 64 + m * 16 + lr) * 32 + lk);
#pragma unroll
    for (int n = 0; n < 4; ++n)
      wf[n] = *(const bf16x8*)(Ws + (wc * 64 + n * 16 + lr) * 32 + lk);
#pragma unroll
    for (int m = 0; m < 4; ++m)
#pragma unroll
      for (int n = 0; n < 4; ++n)
        acc[m][n] = __builtin_amdgcn_mfma_f32_16x16x32_bf16(af[m], wf[n], acc[m][n], 0, 0, 0);
    __syncthreads();
  }
  int rowb = m0 + wr * 64 + (lane >> 4) * 4;
#pragma unroll
  for (int m = 0; m < 4; ++m) {
#pragma unroll
    for (int n = 0; n < 4; ++n) {
      int scol = nl0 + wc * 64 + n * 16 + lr;
      float bcol = seg.bias[scol];
#pragma unroll
      for (int r = 0; r < 4; ++r) {
        int row = rowb + m * 16 + r;
        float val = (acc[m][n][r] + bcol) * seg.ascale;
        if (seg.mode == 0) {
          seg.outb[(size_t)row * 1024 + scol] = f2bf(val);
        } else if (seg.mode == 1) {
          size_t idx = (size_t)row * 1024 + scol;
          seg.outf[idx] = seg.res[idx] + seg.gamma[scol] * val;
        } else {
          int bb = row >> seg.sk;
          int ss = row & ((1 << seg.sk) - 1);
          int h = scol >> 6, d = scol & 63;
          seg.outb[((((size_t)bb * 16 + h) * 64 + d) << seg.sk) + ss] = f2bf(val);
        }
      }
    }
  }
}

// ================= 256x256 8-phase FP8 GEMM (T2+T3+T4+T5), seg-fused epilogue =================
// A fp8 [M,1024], W fp8 [1024,1024] per seg. BK=64 bytes. 16B-granule XOR swizzle
// (granule ^ (row&3)) via pre-swizzled global source; frag ds_read_b64.
__global__ __launch_bounds__(512, 2) void gemm256f8_kernel(
    const u8* __restrict__ A, Seg s0, Seg s1, Seg s2,
    int mtiles, int nt_shift) {
  const int K = 1024;
  int ntiles = 1 << nt_shift;
  int nwg = mtiles * ntiles;
  int cpx = nwg >> 3;
  int bid = blockIdx.x;
  int swz = (bid & 7) * cpx + (bid >> 3);
  int mt = swz >> nt_shift, nt = swz & (ntiles - 1);
  int m0 = mt * 256;
  int si = nt >> 2;
  Seg seg = (si == 0) ? s0 : (si == 1) ? s1 : s2;
  int nl0 = (nt & 3) * 256;  // seg-local col base

  int t = threadIdx.x, lane = t & 63, wv = t >> 6;
  int wm = wv >> 2, wn = wv & 3;
  int lr = lane & 15, lg = lane >> 4;

  __shared__ u8 AB[2][2][256 * 64];  // [buf][0=A,1=B] : 64 KiB
  u8* ldsA0 = &AB[0][0][0];
  u8* ldsB0 = &AB[0][1][0];
  u8* ldsA1 = &AB[1][0][0];
  u8* ldsB1 = &AB[1][1][0];

  // staging: t covers 128 rows x 4 granules(16B) per half-tile; source granule
  // pre-swizzled (c ^ (row&3)) so LDS dest stays linear (rule #21).
  int r0 = t >> 2, c0 = t & 3;
  int cs0 = (c0 ^ (r0 & 3)) * 16;
  const u8* gA = A + (size_t)(m0 + r0) * K + cs0;
  const u8* gB = (const u8*)seg.W + (size_t)(nl0 + r0) * K + cs0;

  auto STG_A = [&](u8* base, int kt) {
    __builtin_amdgcn_global_load_lds((const as1_void*)(gA + kt * 64),
                                     (as3_void*)(base + t * 16), 16, 0, 0);
    __builtin_amdgcn_global_load_lds((const as1_void*)(gA + (size_t)128 * K + kt * 64),
                                     (as3_void*)(base + 8192 + t * 16), 16, 0, 0);
  };
  auto STG_B = [&](u8* base, int kt) {
    __builtin_amdgcn_global_load_lds((const as1_void*)(gB + kt * 64),
                                     (as3_void*)(base + t * 16), 16, 0, 0);
    __builtin_amdgcn_global_load_lds((const as1_void*)(gB + (size_t)128 * K + kt * 64),
                                     (as3_void*)(base + 8192 + t * 16), 16, 0, 0);
  };

  f32x4 acc[8][4] = {};
  long aX[4][2], bX[2][2], bY[2][2];
  int gq0 = lg >> 1, gsub = (lg & 1) * 8;

  auto LD_A = [&](const u8* base, int mo) {
#pragma unroll
    for (int m = 0; m < 4; ++m) {
      int row = wm * 128 + (mo + m) * 16 + lr;
      const u8* rp = base + row * 64;
      int sw = row & 3;
      aX[m][0] = *(const long*)(rp + ((gq0 ^ sw) * 16) + gsub);
      aX[m][1] = *(const long*)(rp + (((2 + gq0) ^ sw) * 16) + gsub);
    }
  };
  auto LD_B = [&](long (&dst)[2][2], const u8* base, int no) {
#pragma unroll
    for (int n = 0; n < 2; ++n) {
      int row = wn * 64 + (no + n) * 16 + lr;
      const u8* rp = base + row * 64;
      int sw = row & 3;
      dst[n][0] = *(const long*)(rp + ((gq0 ^ sw) * 16) + gsub);
      dst[n][1] = *(const long*)(rp + (((2 + gq0) ^ sw) * 16) + gsub);
    }
  };
  auto QD = [&](long (&bf)[2][2], int mo, int no) {
#pragma unroll
    for (int m = 0; m < 4; ++m)
#pragma unroll
      for (int n = 0; n < 2; ++n) {
        acc[mo + m][no + n] = __builtin_amdgcn_mfma_f32_16x16x32_fp8_fp8(
            aX[m][0], bf[n][0], acc[mo + m][no + n], 0, 0, 0);
        acc[mo + m][no + n] = __builtin_amdgcn_mfma_f32_16x16x32_fp8_fp8(
            aX[m][1], bf[n][1], acc[mo + m][no + n], 0, 0, 0);
      }
  };

  // prologue: kt0 -> buf0, kt1 -> buf1 (4 loads each)
  STG_A(ldsA0, 0); STG_B(ldsB0, 0);
  STG_A(ldsA1, 1); STG_B(ldsB1, 1);
  VMCNT(4);  // buf0 retired; buf1 in flight
  BAR();

  const int NIT = K / 128;  // 8
#pragma unroll 1
  for (int it = 0; it < NIT; ++it) {
    bool st = (it + 1 < NIT);
    int ktA = 2 * it;
    // ---- K-tile A (buf0) ----
    LD_A(ldsA0, 0); LD_B(bX, ldsB0, 0);
    BAR(); LGKM0();
    __builtin_amdgcn_s_setprio(1); QD(bX, 0, 0); __builtin_amdgcn_s_setprio(0);
    BAR();
    LD_B(bY, ldsB0, 2);
    BAR(); LGKM0();
    __builtin_amdgcn_s_setprio(1); QD(bY, 0, 2); __builtin_amdgcn_s_setprio(0);
    BAR();
    LD_A(ldsA0, 4);
    if (st) STG_B(ldsB0, ktA + 2);
    BAR(); LGKM0();
    __builtin_amdgcn_s_setprio(1); QD(bY, 4, 2); __builtin_amdgcn_s_setprio(0);
    BAR();
    if (st) { STG_A(ldsA0, ktA + 2); VMCNT(4); } else { VMCNT(0); }
    BAR();
    __builtin_amdgcn_s_setprio(1); QD(bX, 4, 0); __builtin_amdgcn_s_setprio(0);
    BAR();
    // ---- K-tile B (buf1) ----
    LD_A(ldsA1, 0); LD_B(bX, ldsB1, 0);
    BAR(); LGKM0();
    __builtin_amdgcn_s_setprio(1); QD(bX, 0, 0); __builtin_amdgcn_s_setprio(0);
    BAR();
    LD_B(bY, ldsB1, 2);
    BAR(); LGKM0();
    __builtin_amdgcn_s_setprio(1); QD(bY, 0, 2); __builtin_amdgcn_s_setprio(0);
    BAR();
    LD_A(ldsA1, 4);
    if (st) STG_B(ldsB1, ktA + 3);
    BAR(); LGKM0();
    __builtin_amdgcn_s_setprio(1); QD(bY, 4, 2); __builtin_amdgcn_s_setprio(0);
    BAR();
    if (st) { STG_A(ldsA1, ktA + 3); VMCNT(4); }
    BAR();
    __builtin_amdgcn_s_setprio(1); QD(bX, 4, 0); __builtin_amdgcn_s_setprio(0);
    BAR();
  }

  // epilogue
  int rowb = m0 + wm * 128 + lg * 4;
#pragma unroll
  for (int mi = 0; mi < 8; ++mi) {
#pragma unroll
    for (int n = 0; n < 4; ++n) {
      int scol = nl0 + wn * 64 + n * 16 + lr;
      float bcol = seg.bias[scol];
#pragma unroll
      for (int r = 0; r < 4; ++r) {
        int row = rowb + mi * 16 + r;
        float val = (acc[mi][n][r] + bcol) * seg.ascale;
        if (seg.mode == 0) {
          seg.outb[(size_t)row * 1024 + scol] = f2bf(val);
        } else if (seg.mode == 1) {
          size_t idx = (size_t)row * 1024 + scol;
          seg.outf[idx] = seg.res[idx] + seg.gamma[scol] * val;
        } else {
          int bb = row >> seg.sk;
          int ss = row & ((1 << seg.sk) - 1);
          int h = scol >> 6, d = scol & 63;
          seg.outb[((((size_t)bb * 16 + h) * 64 + d) << seg.sk) + ss] = f2bf(val);
        }
      }
    }
  }
}

// ---------------- flash attention v3 (unchanged math; ctx out bf16 or fp8) ----------------
__global__ __launch_bounds__(256, 4) void attn_kernel(
    const u16* __restrict__ Q, const u16* __restrict__ Kmat,
    const u16* __restrict__ Vt, void* __restrict__ ctx,
    int Sq, int Sk, int nq_shift, int fp8out) {
  int f = blockIdx.x;
  int xcd = f & 7, slot = f >> 3;
  int group = xcd * 16 + (slot >> nq_shift);
  int qt = slot & ((1 << nq_shift) - 1);
  int b = group >> 4, h = group & 15;
  int t = threadIdx.x, lane = t & 63, wv = t >> 6;
  int l31 = lane & 31, hi = lane >> 5;

  __shared__ u16 Ks[2][64 * 64];
  __shared__ u16 Vs[2][64 * 64];

  int q0 = qt * 128 + wv * 32;
  const u16* Qb = Q + (size_t)(b * Sq + q0 + l31) * 1024 + h * 64 + hi * 8;
  bf16x8 qf[4];
#pragma unroll
  for (int ds = 0; ds < 4; ++ds) qf[ds] = *(const bf16x8*)(Qb + ds * 16);

  int trow = t >> 3, tc = t & 7;
  int sc = (tc ^ (trow & 7)) * 8;
  const u16* gk = Kmat + (size_t)(b * Sk + trow) * 1024 + h * 64 + sc;
  const u16* gv = Vt + (size_t)((b * 16 + h) * 64 + trow) * Sk + sc;

  auto STAGE = [&](int buf, int kt) {
    const u16* k0 = gk + (size_t)(kt * 64) * 1024;
    const u16* v0 = gv + kt * 64;
    __builtin_amdgcn_global_load_lds((const as1_void*)k0, (as3_void*)(Ks[buf] + t * 8), 16, 0, 0);
    __builtin_amdgcn_global_load_lds((const as1_void*)(k0 + (size_t)32 * 1024), (as3_void*)(Ks[buf] + 2048 + t * 8), 16, 0, 0);
    __builtin_amdgcn_global_load_lds((const as1_void*)v0, (as3_void*)(Vs[buf] + t * 8), 16, 0, 0);
    __builtin_amdgcn_global_load_lds((const as1_void*)(v0 + (size_t)32 * Sk), (as3_void*)(Vs[buf] + 2048 + t * 8), 16, 0, 0);
  };

  STAGE(0, 0);
  __syncthreads();

  f32x16 acc0 = {}, acc1 = {};
  float m_run = -1e30f, l_run = 0.f;
  int sw = l31 & 7;

  int nt = Sk >> 6;
  for (int kt = 0; kt < nt; ++kt) {
    int cur = kt & 1;
    if (kt + 1 < nt) STAGE(cur ^ 1, kt + 1);
    const u16* kb = Ks[cur];
    f32x16 s0v = {}, s1v = {};
    __builtin_amdgcn_s_setprio(1);
#pragma unroll
    for (int ds = 0; ds < 4; ++ds) {
      int blk = 2 * ds + hi;
      bf16x8 ka0 = *(const bf16x8*)(kb + l31 * 64 + ((blk ^ sw) * 8));
      bf16x8 ka1 = *(const bf16x8*)(kb + (32 + l31) * 64 + ((blk ^ sw) * 8));
      s0v = __builtin_amdgcn_mfma_f32_32x32x16_bf16(ka0, qf[ds], s0v, 0, 0, 0);
      s1v = __builtin_amdgcn_mfma_f32_32x32x16_bf16(ka1, qf[ds], s1v, 0, 0, 0);
    }
    __builtin_amdgcn_s_setprio(0);
    float mx = s0v[0];
#pragma unroll
    for (int i = 1; i < 16; ++i) mx = fmaxf(mx, s0v[i]);
#pragma unroll
    for (int i = 0; i < 16; ++i) mx = fmaxf(mx, s1v[i]);
    mx = fmaxf(mx, __shfl_xor(mx, 32));
    if (__any(mx > m_run + 8.f)) {
      float mnew = fmaxf(m_run, mx);
      float fac = __builtin_amdgcn_exp2f(m_run - mnew);
#pragma unroll
      for (int r = 0; r < 16; ++r) {
        int src = (r & 3) + 8 * (r >> 2) + 4 * hi;
        float fr = __shfl(fac, src);
        acc0[r] *= fr;
        acc1[r] *= fr;
      }
      l_run *= fac;
      m_run = mnew;
    }
    float sum = 0.f;
#pragma unroll
    for (int i = 0; i < 16; ++i) {
      s0v[i] = __builtin_amdgcn_exp2f(s0v[i] - m_run);
      sum += s0v[i];
    }
#pragma unroll
    for (int i = 0; i < 16; ++i) {
      s1v[i] = __builtin_amdgcn_exp2f(s1v[i] - m_run);
      sum += s1v[i];
    }
    sum += __shfl_xor(sum, 32);
    l_run += sum;
    bf16x8 pa[4];
#pragma unroll
    for (int g = 0; g < 2; ++g) {
      const f32x16& s = g ? s1v : s0v;
#pragma unroll
      for (int half = 0; half < 2; ++half) {
        int o = half * 8;
        uint32_t a0, a1, b0, b1;
        asm("v_cvt_pk_bf16_f32 %0, %1, %2" : "=v"(a0) : "v"(s[o + 0]), "v"(s[o + 1]));
        asm("v_cvt_pk_bf16_f32 %0, %1, %2" : "=v"(a1) : "v"(s[o + 2]), "v"(s[o + 3]));
        asm("v_cvt_pk_bf16_f32 %0, %1, %2" : "=v"(b0) : "v"(s[o + 4]), "v"(s[o + 5]));
        asm("v_cvt_pk_bf16_f32 %0, %1, %2" : "=v"(b1) : "v"(s[o + 6]), "v"(s[o + 7]));
        asm("v_permlane32_swap_b32 %0, %1" : "+v"(a0), "+v"(b0));
        asm("v_permlane32_swap_b32 %0, %1" : "+v"(a1), "+v"(b1));
        u32x4 w;
        w[0] = a0; w[1] = a1; w[2] = b0; w[3] = b1;
        pa[g * 2 + half] = __builtin_bit_cast(bf16x8, w);
      }
    }
    const u16* vb = Vs[cur];
    __builtin_amdgcn_s_setprio(1);
#pragma unroll
    for (int ks = 0; ks < 4; ++ks) {
      int blk = 2 * ks + hi;
      bf16x8 vf0 = *(const bf16x8*)(vb + l31 * 64 + ((blk ^ sw) * 8));
      bf16x8 vf1 = *(const bf16x8*)(vb + (32 + l31) * 64 + ((blk ^ sw) * 8));
      acc0 = __builtin_amdgcn_mfma_f32_32x32x16_bf16(pa[ks], vf0, acc0, 0, 0, 0);
      acc1 = __builtin_amdgcn_mfma_f32_32x32x16_bf16(pa[ks], vf1, acc1, 0, 0, 0);
    }
    __builtin_amdgcn_s_setprio(0);
    __syncthreads();
  }
  float linv = 1.0f / l_run;
  if (fp8out) {
    u8* cb = (u8*)ctx + (size_t)(b * Sq + q0) * 1024 + h * 64;
#pragma unroll
    for (int r = 0; r < 16; ++r) {
      int src = (r & 3) + 8 * (r >> 2) + 4 * hi;
      float li = __shfl(linv, src);
      cb[(size_t)src * 1024 + l31] = f2fp8(acc0[r] * li);
      cb[(size_t)src * 1024 + 32 + l31] = f2fp8(acc1[r] * li);
    }
  } else {
    u16* cb = (u16*)ctx + (size_t)(b * Sq + q0) * 1024 + h * 64;
#pragma unroll
    for (int r = 0; r < 16; ++r) {
      int src = (r & 3) + 8 * (r >> 2) + 4 * hi;
      float li = __shfl(linv, src);
      cb[(size_t)src * 1024 + l31] = f2bf(acc0[r] * li);
      cb[(size_t)src * 1024 + 32 + l31] = f2bf(acc1[r] * li);
    }
  }
}

extern "C" void kernel_launch(void* const* d_in, const int* in_sizes, int n_in,
                              void* d_out, int out_size, void* d_ws, size_t ws_size,
                              hipStream_t stream) {
  const float* v = (const float*)d_in[0];
  const float* l = (const float*)d_in[1];
  const float* ln_v_g = (const float*)d_in[2];
  const float* ln_v_b = (const float*)d_in[3];
  const float* ln_l_g = (const float*)d_in[4];
  const float* ln_l_b = (const float*)d_in[5];
  const float* gamma_v = (const float*)d_in[6];
  const float* gamma_l = (const float*)d_in[7];
  const float* Wf[8];
  const float* Bf[8];
  for (int i = 0; i < 8; ++i) {
    Wf[i] = (const float*)d_in[8 + 2 * i];
    Bf[i] = (const float*)d_in[9 + 2 * i];
  }
  float* v_out = (float*)d_out;
  float* l_out = v_out + (size_t)16384 * 1024;

  char* p = (char*)d_ws;
  auto alloc = [&](size_t bytes) {
    char* r = p;
    p += (bytes + 255) & ~(size_t)255;
    return r;
  };
  // fp8 weights: Wq_v2l(0), Wk_l2v(5), Wv_l2v(6), Wo_v2l(3)
  u8* Wq_v8 = (u8*)alloc(1 << 20);
  u8* Wk_l8 = (u8*)alloc(1 << 20);
  u8* Wv_l8 = (u8*)alloc(1 << 20);
  u8* Wo_v8 = (u8*)alloc(1 << 20);
  // bf16 weights: Wk_v2l(1), Wv_v2l(2), Wq_l2v(4), Wo_l2v(7)
  u16* Wk_vb = (u16*)alloc(2 << 20);
  u16* Wv_vb = (u16*)alloc(2 << 20);
  u16* Wq_lb = (u16*)alloc(2 << 20);
  u16* Wo_lb = (u16*)alloc(2 << 20);
  u8*  vn8  = (u8*)alloc((size_t)16384 * 1024);      // LN(v) fp8
  u16* lnm  = (u16*)alloc((size_t)4096 * 1024 * 2);  // LN(l) bf16; later ctx_l
  u16* bufA = (u16*)alloc((size_t)16384 * 1024 * 2); // Q_v2l -> K_l2v
  u16* bufB = (u16*)alloc((size_t)4096 * 1024 * 2);  // Q_l2v
  u16* bufC = (u16*)alloc((size_t)4096 * 1024 * 2);  // Vt_v2l
  u16* bufD = (u16*)alloc((size_t)16384 * 1024 * 2); // Vt_l2v
  u16* bufF = (u16*)alloc((size_t)4096 * 1024 * 2);  // K_v2l
  u8*  ctxv = (u8*)alloc((size_t)16384 * 1024);      // ctx_v fp8

  const float QSC = 0.125f * 1.4426950408889634f;
  Seg zs = {};

  cvt8_kernel<<<dim3(1024, 8), 256, 0, stream>>>(
      (const float4*)Wf[0], (const float4*)Wf[5], (const float4*)Wf[6], (const float4*)Wf[3],
      (const float4*)Wf[1], (const float4*)Wf[2], (const float4*)Wf[4], (const float4*)Wf[7],
      (uint32_t*)Wq_v8, (uint32_t*)Wk_l8, (uint32_t*)Wv_l8, (uint32_t*)Wo_v8,
      (ushort4*)Wk_vb, (ushort4*)Wv_vb, (ushort4*)Wq_lb, (ushort4*)Wo_lb);
  ln_kernel<1><<<16384, 256, 0, stream>>>(v, ln_v_g, ln_v_b, vn8);
  ln_kernel<0><<<4096, 256, 0, stream>>>(l, ln_l_g, ln_l_b, lnm);

  // lnm-fused3: Q_l2v | K_v2l | Vt_v2l
  {
    Seg a = {Wq_lb, Bf[4], bufB, nullptr, nullptr, nullptr, 0, 0, QSC};
    Seg b = {Wk_vb, Bf[1], bufF, nullptr, nullptr, nullptr, 0, 0, 1.0f};
    Seg c = {Wv_vb, Bf[2], bufC, nullptr, nullptr, nullptr, 2, 9, 1.0f};
    gemm128_kernel<<<dim3(32, 24), 256, 0, stream>>>(lnm, a, b, c);
  }
  // Q_v2l
  {
    Seg q = {Wq_v8, Bf[0], bufA, nullptr, nullptr, nullptr, 0, 0, QSC};
    gemm256f8_kernel<<<dim3(256), 512, 0, stream>>>(vn8, q, zs, zs, 64, 2);
  }
  // attn v2l -> ctxv (fp8)
  attn_kernel<<<dim3(2048), 256, 0, stream>>>(bufA, bufF, bufC, ctxv, 2048, 512, 4, 1);
  // vn-fused2: K_l2v | Vt_l2v (bufA reusable now)
  {
    Seg k = {Wk_l8, Bf[5], bufA, nullptr, nullptr, nullptr, 0, 0, 1.0f};
    Seg vv = {Wv_l8, Bf[6], bufD, nullptr, nullptr, nullptr, 2, 11, 1.0f};
    gemm256f8_kernel<<<dim3(512), 512, 0, stream>>>(vn8, k, vv, zs, 64, 3);
  }
  // O-proj v: ctxv @ Wo_v2l + residual
  {
    Seg o = {Wo_v8, Bf[3], nullptr, v_out, v, gamma_v, 1, 0, 1.0f};
    gemm256f8_kernel<<<dim3(256), 512, 0, stream>>>(ctxv, o, zs, zs, 64, 2);
  }
  // attn l2v -> ctx_l (bf16, reuse lnm region)
  attn_kernel<<<dim3(512), 256, 0, stream>>>(bufB, bufA, bufD, lnm, 512, 2048, 2, 0);
  // O-proj l
  {
    Seg o = {Wo_lb, Bf[7], nullptr, l_out, l, gamma_l, 1, 0, 1.0f};
    gemm128_kernel<<<dim3(32, 8), 256, 0, stream>>>(lnm, o, zs, zs);
  }
}

// Round 7
// 506.346 us; speedup vs baseline: 1.0081x; 1.0081x over previous
//
#include <hip/hip_runtime.h>
#include <hip/hip_bf16.h>
#include <stdint.h>

typedef __bf16 bf16x8 __attribute__((ext_vector_type(8)));
typedef float f32x4 __attribute__((ext_vector_type(4)));
typedef float f32x16 __attribute__((ext_vector_type(16)));
typedef uint32_t u32x4 __attribute__((ext_vector_type(4)));
typedef unsigned short u16;

typedef __attribute__((address_space(1))) void as1_void;
typedef __attribute__((address_space(3))) void as3_void;

#define BAR() __builtin_amdgcn_s_barrier()
#define VMCNT(n) asm volatile("s_waitcnt vmcnt(" #n ")" ::: "memory")
#define LGKM0() asm volatile("s_waitcnt lgkmcnt(0)" ::: "memory")

__device__ __forceinline__ u16 f2bf(float f) {
  uint32_t u = __float_as_uint(f);
  u += 0x7fffu + ((u >> 16) & 1u);
  return (u16)(u >> 16);
}

// epilogue segment descriptor (uniform per block)
struct Seg {
  const u16* W;         // bf16 weight [1024,1024] (row = out col, torch W)
  const float* bias;    // [1024]
  u16* outb;            // mode 0/2 bf16 out
  float* outf;          // mode 1 fp32 out
  const float* res;     // mode 1 residual
  const float* gamma;   // mode 1 gamma
  int mode;             // 0 = bf16 rowmajor, 1 = fp32 res+gamma, 2 = Vt bf16
  int sk;               // mode2 shift
  float ascale;
};

// ---------------- fp32 -> bf16 convert (all 8 weights, one dispatch) ----------------
__global__ __launch_bounds__(256) void cvt8_kernel(
    const float4* s0, const float4* s1, const float4* s2, const float4* s3,
    const float4* s4, const float4* s5, const float4* s6, const float4* s7,
    ushort4* d0, ushort4* d1, ushort4* d2, ushort4* d3,
    ushort4* d4, ushort4* d5, ushort4* d6, ushort4* d7) {
  const float4* s; ushort4* d;
  switch (blockIdx.y) {
    case 0: s = s0; d = d0; break;
    case 1: s = s1; d = d1; break;
    case 2: s = s2; d = d2; break;
    case 3: s = s3; d = d3; break;
    case 4: s = s4; d = d4; break;
    case 5: s = s5; d = d5; break;
    case 6: s = s6; d = d6; break;
    default: s = s7; d = d7; break;
  }
  int i = blockIdx.x * 256 + threadIdx.x;
  float4 v = s[i];
  ushort4 o;
  o.x = f2bf(v.x); o.y = f2bf(v.y); o.z = f2bf(v.z); o.w = f2bf(v.w);
  d[i] = o;
}

// ---------------- layernorm fp32 -> bf16, D=1024 ----------------
__global__ __launch_bounds__(256) void ln_kernel(const float* __restrict__ x,
                                                 const float* __restrict__ g,
                                                 const float* __restrict__ b,
                                                 u16* __restrict__ out) {
  int row = blockIdx.x;
  int t = threadIdx.x;
  const float4* xr = (const float4*)(x + (size_t)row * 1024);
  float4 v = xr[t];
  float s = v.x + v.y + v.z + v.w;
  float s2 = v.x * v.x + v.y * v.y + v.z * v.z + v.w * v.w;
#pragma unroll
  for (int off = 1; off < 64; off <<= 1) {
    s += __shfl_xor(s, off);
    s2 += __shfl_xor(s2, off);
  }
  __shared__ float red[8];
  int wv = t >> 6;
  if ((t & 63) == 0) { red[wv] = s; red[4 + wv] = s2; }
  __syncthreads();
  s = red[0] + red[1] + red[2] + red[3];
  s2 = red[4] + red[5] + red[6] + red[7];
  float mu = s * (1.0f / 1024.0f);
  float var = s2 * (1.0f / 1024.0f) - mu * mu;
  float rstd = rsqrtf(var + 1e-5f);
  const float4 gv = ((const float4*)g)[t];
  const float4 bv = ((const float4*)b)[t];
  ushort4 o;
  o.x = f2bf((v.x - mu) * rstd * gv.x + bv.x);
  o.y = f2bf((v.y - mu) * rstd * gv.y + bv.y);
  o.z = f2bf((v.z - mu) * rstd * gv.z + bv.z);
  o.w = f2bf((v.w - mu) * rstd * gv.w + bv.w);
  ((ushort4*)out)[(size_t)row * 256 + t] = o;
}

// ================= gemm_v7: 128x128 tile, BK=32, 3-deep prefetch, 3 blocks/CU =================
// C[M, ntiles*128] = A[M,1024] @ W^T + bias, seg-fused epilogues (seg = nt>>3).
// 4 waves (2x2), per-wave 64x64 output. LDS 3 slots x (A 8KB + B 8KB) = 48 KiB.
// Granule-XOR swizzle (16B granule ^ (row&3)) via pre-swizzled global source.
// Counted vmcnt ladder: stage kt+3 each iter; vmcnt(8) ensures kt+1 landed.
// XCD decode: mt-chunks per XCD (requires mtiles % 8 == 0).
__global__ __launch_bounds__(256, 3) void gemm_v7(
    const u16* __restrict__ A, Seg s0, Seg s1, Seg s2,
    int mtiles, int ntiles) {
  const int K = 1024;
  int hwid = blockIdx.x;
  int xcd = hwid & 7, q = hwid >> 3;
  int mchunk = mtiles >> 3;
  int mt = xcd * mchunk + q / ntiles;
  int nt = q % ntiles;
  int m0 = mt * 128;
  int si = nt >> 3;
  Seg seg = (si == 0) ? s0 : (si == 1) ? s1 : s2;
  int nl0 = (nt & 7) * 128;

  int t = threadIdx.x, lane = t & 63, wv = t >> 6;
  int wr = wv >> 1, wc = wv & 1;
  int lr = lane & 15, lg = lane >> 4;

  __shared__ u16 SA[3][128 * 32];
  __shared__ u16 SB[3][128 * 32];

  // staging: thread t owns rows (t>>2) and (t>>2)+64, granule t&3 (16B each);
  // source granule pre-swizzled: (c ^ (row&3)); (row+64)&3 == row&3.
  int row0 = t >> 2, c0 = t & 3;
  int sco = (c0 ^ (row0 & 3)) * 8;  // u16 elems
  const u16* gA0 = A + (size_t)(m0 + row0) * K + sco;
  const u16* gB0 = seg.W + (size_t)(nl0 + row0) * K + sco;

  auto STAGE = [&](int slot, int kt) {
    __builtin_amdgcn_global_load_lds((const as1_void*)(gA0 + kt * 32),
                                     (as3_void*)(&SA[slot][0] + t * 8), 16, 0, 0);
    __builtin_amdgcn_global_load_lds((const as1_void*)(gA0 + (size_t)64 * K + kt * 32),
                                     (as3_void*)(&SA[slot][0] + 2048 + t * 8), 16, 0, 0);
    __builtin_amdgcn_global_load_lds((const as1_void*)(gB0 + kt * 32),
                                     (as3_void*)(&SB[slot][0] + t * 8), 16, 0, 0);
    __builtin_amdgcn_global_load_lds((const as1_void*)(gB0 + (size_t)64 * K + kt * 32),
                                     (as3_void*)(&SB[slot][0] + 2048 + t * 8), 16, 0, 0);
  };

  f32x4 acc[4][4] = {};

  STAGE(0, 0); STAGE(1, 1); STAGE(2, 2);
  VMCNT(8);  // slot0's 4 loads retired
  BAR();

  int slot = 0;
  const int NKT = K / 32;  // 32
#pragma unroll 1
  for (int kt = 0; kt < NKT; ++kt) {
    bf16x8 aX[4], bX[4];
#pragma unroll
    for (int m = 0; m < 4; ++m) {
      int row = wr * 64 + m * 16 + lr;
      aX[m] = *(const bf16x8*)(&SA[slot][0] + row * 32 + ((lg ^ (row & 3)) * 8));
    }
#pragma unroll
    for (int n = 0; n < 4; ++n) {
      int row = wc * 64 + n * 16 + lr;
      bX[n] = *(const bf16x8*)(&SB[slot][0] + row * 32 + ((lg ^ (row & 3)) * 8));
    }
    LGKM0();            // my reads complete (data latched in regs)
    BAR();              // all waves' reads done -> slot safe to overwrite
    if (kt + 3 < NKT) STAGE(slot, kt + 3);
    __builtin_amdgcn_s_setprio(1);
#pragma unroll
    for (int m = 0; m < 4; ++m)
#pragma unroll
      for (int n = 0; n < 4; ++n)
        acc[m][n] = __builtin_amdgcn_mfma_f32_16x16x32_bf16(aX[m], bX[n], acc[m][n], 0, 0, 0);
    __builtin_amdgcn_s_setprio(0);
    if (kt + 3 < NKT) { VMCNT(8); }        // kt+1's 4 loads (issued 2 iters ago) landed
    else if (kt + 3 == NKT) { VMCNT(4); }  // in-flight kt+1,kt+2 = 8 -> wait kt+1
    else if (kt + 2 == NKT) { VMCNT(0); }  // in-flight kt+1 = 4 -> wait all
    BAR();              // no wave laps into reading next slot early
    slot = (slot == 2) ? 0 : slot + 1;
  }

  // epilogue: per-wave 64x64, D layout col = lane&15, row = (lane>>4)*4 + r
  int rowb = m0 + wr * 64 + (lane >> 4) * 4;
#pragma unroll
  for (int m = 0; m < 4; ++m) {
#pragma unroll
    for (int n = 0; n < 4; ++n) {
      int scol = nl0 + wc * 64 + n * 16 + lr;
      float bcol = seg.bias[scol];
#pragma unroll
      for (int r = 0; r < 4; ++r) {
        int row = rowb + m * 16 + r;
        float val = (acc[m][n][r] + bcol) * seg.ascale;
        if (seg.mode == 0) {
          seg.outb[(size_t)row * 1024 + scol] = f2bf(val);
        } else if (seg.mode == 1) {
          size_t idx = (size_t)row * 1024 + scol;
          seg.outf[idx] = seg.res[idx] + seg.gamma[scol] * val;
        } else {
          int bb = row >> seg.sk;
          int ss = row & ((1 << seg.sk) - 1);
          int h = scol >> 6, d = scol & 63;
          seg.outb[((((size_t)bb * 16 + h) * 64 + d) << seg.sk) + ss] = f2bf(val);
        }
      }
    }
  }
}

// ---------------- flash attention v3: swapped QK^T 32x32, in-reg softmax, LDS K/V ----------------
// ctx written IN-PLACE over Q (each block reads exactly the q-rows x head-slice
// region it writes; Q is register-resident before the first barrier).
__global__ __launch_bounds__(256, 4) void attn_kernel(
    const u16* __restrict__ Q, const u16* __restrict__ Kmat,
    const u16* __restrict__ Vt, u16* __restrict__ ctx,
    int Sq, int Sk, int nq_shift) {
  int f = blockIdx.x;
  int xcd = f & 7, slot = f >> 3;
  int group = xcd * 16 + (slot >> nq_shift);
  int qt = slot & ((1 << nq_shift) - 1);
  int b = group >> 4, h = group & 15;
  int t = threadIdx.x, lane = t & 63, wv = t >> 6;
  int l31 = lane & 31, hi = lane >> 5;

  __shared__ u16 Ks[2][64 * 64];
  __shared__ u16 Vs[2][64 * 64];

  int q0 = qt * 128 + wv * 32;
  const u16* Qb = Q + (size_t)(b * Sq + q0 + l31) * 1024 + h * 64 + hi * 8;
  bf16x8 qf[4];
#pragma unroll
  for (int ds = 0; ds < 4; ++ds) qf[ds] = *(const bf16x8*)(Qb + ds * 16);

  int trow = t >> 3, tc = t & 7;
  int sc = (tc ^ (trow & 7)) * 8;
  const u16* gk = Kmat + (size_t)(b * Sk + trow) * 1024 + h * 64 + sc;
  const u16* gv = Vt + (size_t)((b * 16 + h) * 64 + trow) * Sk + sc;

  auto STAGE = [&](int buf, int kt) {
    const u16* k0 = gk + (size_t)(kt * 64) * 1024;
    const u16* v0 = gv + kt * 64;
    __builtin_amdgcn_global_load_lds((const as1_void*)k0, (as3_void*)(Ks[buf] + t * 8), 16, 0, 0);
    __builtin_amdgcn_global_load_lds((const as1_void*)(k0 + (size_t)32 * 1024), (as3_void*)(Ks[buf] + 2048 + t * 8), 16, 0, 0);
    __builtin_amdgcn_global_load_lds((const as1_void*)v0, (as3_void*)(Vs[buf] + t * 8), 16, 0, 0);
    __builtin_amdgcn_global_load_lds((const as1_void*)(v0 + (size_t)32 * Sk), (as3_void*)(Vs[buf] + 2048 + t * 8), 16, 0, 0);
  };

  STAGE(0, 0);
  __syncthreads();

  f32x16 acc0 = {}, acc1 = {};
  float m_run = -1e30f, l_run = 0.f;
  int sw = l31 & 7;

  int nt = Sk >> 6;
  for (int kt = 0; kt < nt; ++kt) {
    int cur = kt & 1;
    if (kt + 1 < nt) STAGE(cur ^ 1, kt + 1);
    const u16* kb = Ks[cur];
    f32x16 s0v = {}, s1v = {};
    __builtin_amdgcn_s_setprio(1);
#pragma unroll
    for (int ds = 0; ds < 4; ++ds) {
      int blk = 2 * ds + hi;
      bf16x8 ka0 = *(const bf16x8*)(kb + l31 * 64 + ((blk ^ sw) * 8));
      bf16x8 ka1 = *(const bf16x8*)(kb + (32 + l31) * 64 + ((blk ^ sw) * 8));
      s0v = __builtin_amdgcn_mfma_f32_32x32x16_bf16(ka0, qf[ds], s0v, 0, 0, 0);
      s1v = __builtin_amdgcn_mfma_f32_32x32x16_bf16(ka1, qf[ds], s1v, 0, 0, 0);
    }
    __builtin_amdgcn_s_setprio(0);
    float mx = s0v[0];
#pragma unroll
    for (int i = 1; i < 16; ++i) mx = fmaxf(mx, s0v[i]);
#pragma unroll
    for (int i = 0; i < 16; ++i) mx = fmaxf(mx, s1v[i]);
    mx = fmaxf(mx, __shfl_xor(mx, 32));
    if (__any(mx > m_run + 8.f)) {
      float mnew = fmaxf(m_run, mx);
      float fac = __builtin_amdgcn_exp2f(m_run - mnew);
#pragma unroll
      for (int r = 0; r < 16; ++r) {
        int src = (r & 3) + 8 * (r >> 2) + 4 * hi;
        float fr = __shfl(fac, src);
        acc0[r] *= fr;
        acc1[r] *= fr;
      }
      l_run *= fac;
      m_run = mnew;
    }
    float sum = 0.f;
#pragma unroll
    for (int i = 0; i < 16; ++i) {
      s0v[i] = __builtin_amdgcn_exp2f(s0v[i] - m_run);
      sum += s0v[i];
    }
#pragma unroll
    for (int i = 0; i < 16; ++i) {
      s1v[i] = __builtin_amdgcn_exp2f(s1v[i] - m_run);
      sum += s1v[i];
    }
    sum += __shfl_xor(sum, 32);
    l_run += sum;
    bf16x8 pa[4];
#pragma unroll
    for (int g = 0; g < 2; ++g) {
      const f32x16& s = g ? s1v : s0v;
#pragma unroll
      for (int half = 0; half < 2; ++half) {
        int o = half * 8;
        uint32_t a0, a1, b0, b1;
        asm("v_cvt_pk_bf16_f32 %0, %1, %2" : "=v"(a0) : "v"(s[o + 0]), "v"(s[o + 1]));
        asm("v_cvt_pk_bf16_f32 %0, %1, %2" : "=v"(a1) : "v"(s[o + 2]), "v"(s[o + 3]));
        asm("v_cvt_pk_bf16_f32 %0, %1, %2" : "=v"(b0) : "v"(s[o + 4]), "v"(s[o + 5]));
        asm("v_cvt_pk_bf16_f32 %0, %1, %2" : "=v"(b1) : "v"(s[o + 6]), "v"(s[o + 7]));
        asm("v_permlane32_swap_b32 %0, %1" : "+v"(a0), "+v"(b0));
        asm("v_permlane32_swap_b32 %0, %1" : "+v"(a1), "+v"(b1));
        u32x4 w;
        w[0] = a0; w[1] = a1; w[2] = b0; w[3] = b1;
        pa[g * 2 + half] = __builtin_bit_cast(bf16x8, w);
      }
    }
    const u16* vb = Vs[cur];
    __builtin_amdgcn_s_setprio(1);
#pragma unroll
    for (int ks = 0; ks < 4; ++ks) {
      int blk = 2 * ks + hi;
      bf16x8 vf0 = *(const bf16x8*)(vb + l31 * 64 + ((blk ^ sw) * 8));
      bf16x8 vf1 = *(const bf16x8*)(vb + (32 + l31) * 64 + ((blk ^ sw) * 8));
      acc0 = __builtin_amdgcn_mfma_f32_32x32x16_bf16(pa[ks], vf0, acc0, 0, 0, 0);
      acc1 = __builtin_amdgcn_mfma_f32_32x32x16_bf16(pa[ks], vf1, acc1, 0, 0, 0);
    }
    __builtin_amdgcn_s_setprio(0);
    __syncthreads();
  }
  float linv = 1.0f / l_run;
  u16* cb = ctx + (size_t)(b * Sq + q0) * 1024 + h * 64;
#pragma unroll
  for (int r = 0; r < 16; ++r) {
    int src = (r & 3) + 8 * (r >> 2) + 4 * hi;
    float li = __shfl(linv, src);
    cb[(size_t)src * 1024 + l31] = f2bf(acc0[r] * li);
    cb[(size_t)src * 1024 + 32 + l31] = f2bf(acc1[r] * li);
  }
}

extern "C" void kernel_launch(void* const* d_in, const int* in_sizes, int n_in,
                              void* d_out, int out_size, void* d_ws, size_t ws_size,
                              hipStream_t stream) {
  const float* v = (const float*)d_in[0];
  const float* l = (const float*)d_in[1];
  const float* ln_v_g = (const float*)d_in[2];
  const float* ln_v_b = (const float*)d_in[3];
  const float* ln_l_g = (const float*)d_in[4];
  const float* ln_l_b = (const float*)d_in[5];
  const float* gamma_v = (const float*)d_in[6];
  const float* gamma_l = (const float*)d_in[7];
  const float* Wf[8];
  const float* Bf[8];
  for (int i = 0; i < 8; ++i) {
    Wf[i] = (const float*)d_in[8 + 2 * i];
    Bf[i] = (const float*)d_in[9 + 2 * i];
  }
  float* v_out = (float*)d_out;
  float* l_out = v_out + (size_t)16384 * 1024;

  char* p = (char*)d_ws;
  auto alloc = [&](size_t bytes) {
    char* r = p;
    p += (bytes + 255) & ~(size_t)255;
    return r;
  };
  u16* Wbf[8];
  for (int i = 0; i < 8; ++i) Wbf[i] = (u16*)alloc((size_t)1024 * 1024 * 2);
  u16* vn   = (u16*)alloc((size_t)16384 * 1024 * 2);  // LN(v)
  u16* lnm  = (u16*)alloc((size_t)4096 * 1024 * 2);   // LN(l)
  u16* bufA = (u16*)alloc((size_t)16384 * 1024 * 2);  // Q_v2l -> ctx_v (in-place) -> K_l2v
  u16* bufB = (u16*)alloc((size_t)4096 * 1024 * 2);   // Q_l2v -> ctx_l (in-place)
  u16* bufC = (u16*)alloc((size_t)4096 * 1024 * 2);   // Vt_v2l
  u16* bufD = (u16*)alloc((size_t)16384 * 1024 * 2);  // Vt_l2v
  u16* bufF = (u16*)alloc((size_t)4096 * 1024 * 2);   // K_v2l

  const float QSC = 0.125f * 1.4426950408889634f;  // 1/sqrt(64) * log2(e)
  Seg zs = {};

  cvt8_kernel<<<dim3(1024, 8), 256, 0, stream>>>(
      (const float4*)Wf[0], (const float4*)Wf[1], (const float4*)Wf[2], (const float4*)Wf[3],
      (const float4*)Wf[4], (const float4*)Wf[5], (const float4*)Wf[6], (const float4*)Wf[7],
      (ushort4*)Wbf[0], (ushort4*)Wbf[1], (ushort4*)Wbf[2], (ushort4*)Wbf[3],
      (ushort4*)Wbf[4], (ushort4*)Wbf[5], (ushort4*)Wbf[6], (ushort4*)Wbf[7]);
  ln_kernel<<<16384, 256, 0, stream>>>(v, ln_v_g, ln_v_b, vn);
  ln_kernel<<<4096, 256, 0, stream>>>(l, ln_l_g, ln_l_b, lnm);

  // lnm-fused3: Q_l2v | K_v2l | Vt_v2l   (M=4096, N=3072)
  {
    Seg a = {Wbf[4], Bf[4], bufB, nullptr, nullptr, nullptr, 0, 0, QSC};
    Seg b = {Wbf[1], Bf[1], bufF, nullptr, nullptr, nullptr, 0, 0, 1.0f};
    Seg c = {Wbf[2], Bf[2], bufC, nullptr, nullptr, nullptr, 2, 9, 1.0f};
    gemm_v7<<<dim3(768), 256, 0, stream>>>(lnm, a, b, c, 32, 24);
  }
  // Q_v2l (M=16384, N=1024)
  {
    Seg q = {Wbf[0], Bf[0], bufA, nullptr, nullptr, nullptr, 0, 0, QSC};
    gemm_v7<<<dim3(1024), 256, 0, stream>>>(vn, q, zs, zs, 128, 8);
  }
  // attn v2l: ctx_v in-place into bufA
  attn_kernel<<<dim3(2048), 256, 0, stream>>>(bufA, bufF, bufC, bufA, 2048, 512, 4);
  // O-proj v: ctx_v @ Wo_v2l + residual
  {
    Seg o = {Wbf[3], Bf[3], nullptr, v_out, v, gamma_v, 1, 0, 1.0f};
    gemm_v7<<<dim3(1024), 256, 0, stream>>>(bufA, o, zs, zs, 128, 8);
  }
  // vn-fused2: K_l2v | Vt_l2v  (M=16384, N=2048; bufA free now)
  {
    Seg k = {Wbf[5], Bf[5], bufA, nullptr, nullptr, nullptr, 0, 0, 1.0f};
    Seg vv = {Wbf[6], Bf[6], bufD, nullptr, nullptr, nullptr, 2, 11, 1.0f};
    gemm_v7<<<dim3(2048), 256, 0, stream>>>(vn, k, vv, zs, 128, 16);
  }
  // attn l2v: ctx_l in-place into bufB
  attn_kernel<<<dim3(512), 256, 0, stream>>>(bufB, bufA, bufD, bufB, 512, 2048, 2);
  // O-proj l
  {
    Seg o = {Wbf[7], Bf[7], nullptr, l_out, l, gamma_l, 1, 0, 1.0f};
    gemm_v7<<<dim3(256), 256, 0, stream>>>(bufB, o, zs, zs, 32, 8);
  }
}

// Round 8
// 479.574 us; speedup vs baseline: 1.0644x; 1.0558x over previous
//
#include <hip/hip_runtime.h>
#include <hip/hip_bf16.h>
#include <stdint.h>

typedef __bf16 bf16x8 __attribute__((ext_vector_type(8)));
typedef float f32x4 __attribute__((ext_vector_type(4)));
typedef float f32x16 __attribute__((ext_vector_type(16)));
typedef uint32_t u32x4 __attribute__((ext_vector_type(4)));
typedef unsigned short u16;

typedef __attribute__((address_space(1))) void as1_void;
typedef __attribute__((address_space(3))) void as3_void;

#define BAR() __builtin_amdgcn_s_barrier()
#define VMCNT(n) asm volatile("s_waitcnt vmcnt(" #n ")" ::: "memory")
#define LGKM0() asm volatile("s_waitcnt lgkmcnt(0)" ::: "memory")

__device__ __forceinline__ u16 f2bf(float f) {
  uint32_t u = __float_as_uint(f);
  u += 0x7fffu + ((u >> 16) & 1u);
  return (u16)(u >> 16);
}

// epilogue segment descriptor (uniform per block)
struct Seg {
  const u16* W;         // bf16 weight [1024,1024] (row = out col, torch W)
  const float* bias;    // [1024]
  u16* outb;            // mode 0/2 bf16 out
  float* outf;          // mode 1 fp32 out
  const float* res;     // mode 1 residual
  const float* gamma;   // mode 1 gamma
  int mode;             // 0 = bf16 rowmajor, 1 = fp32 res+gamma, 2 = Vt bf16
  int sk;               // mode2 shift
  float ascale;
};

// ---------------- fp32 -> bf16 convert (all 8 weights, one dispatch) ----------------
__global__ __launch_bounds__(256) void cvt8_kernel(
    const float4* s0, const float4* s1, const float4* s2, const float4* s3,
    const float4* s4, const float4* s5, const float4* s6, const float4* s7,
    ushort4* d0, ushort4* d1, ushort4* d2, ushort4* d3,
    ushort4* d4, ushort4* d5, ushort4* d6, ushort4* d7) {
  const float4* s; ushort4* d;
  switch (blockIdx.y) {
    case 0: s = s0; d = d0; break;
    case 1: s = s1; d = d1; break;
    case 2: s = s2; d = d2; break;
    case 3: s = s3; d = d3; break;
    case 4: s = s4; d = d4; break;
    case 5: s = s5; d = d5; break;
    case 6: s = s6; d = d6; break;
    default: s = s7; d = d7; break;
  }
  int i = blockIdx.x * 256 + threadIdx.x;
  float4 v = s[i];
  ushort4 o;
  o.x = f2bf(v.x); o.y = f2bf(v.y); o.z = f2bf(v.z); o.w = f2bf(v.w);
  d[i] = o;
}

// ---------------- layernorm fp32 -> bf16, D=1024 ----------------
__global__ __launch_bounds__(256) void ln_kernel(const float* __restrict__ x,
                                                 const float* __restrict__ g,
                                                 const float* __restrict__ b,
                                                 u16* __restrict__ out) {
  int row = blockIdx.x;
  int t = threadIdx.x;
  const float4* xr = (const float4*)(x + (size_t)row * 1024);
  float4 v = xr[t];
  float s = v.x + v.y + v.z + v.w;
  float s2 = v.x * v.x + v.y * v.y + v.z * v.z + v.w * v.w;
#pragma unroll
  for (int off = 1; off < 64; off <<= 1) {
    s += __shfl_xor(s, off);
    s2 += __shfl_xor(s2, off);
  }
  __shared__ float red[8];
  int wv = t >> 6;
  if ((t & 63) == 0) { red[wv] = s; red[4 + wv] = s2; }
  __syncthreads();
  s = red[0] + red[1] + red[2] + red[3];
  s2 = red[4] + red[5] + red[6] + red[7];
  float mu = s * (1.0f / 1024.0f);
  float var = s2 * (1.0f / 1024.0f) - mu * mu;
  float rstd = rsqrtf(var + 1e-5f);
  const float4 gv = ((const float4*)g)[t];
  const float4 bv = ((const float4*)b)[t];
  ushort4 o;
  o.x = f2bf((v.x - mu) * rstd * gv.x + bv.x);
  o.y = f2bf((v.y - mu) * rstd * gv.y + bv.y);
  o.z = f2bf((v.z - mu) * rstd * gv.z + bv.z);
  o.w = f2bf((v.w - mu) * rstd * gv.w + bv.w);
  ((ushort4*)out)[(size_t)row * 256 + t] = o;
}

// ================= gemm_v7b: 128x128 tile, BK=32, 3-deep prefetch, 3 blocks/CU =================
// Swizzle key f(r) = (r>>1)&3 — bank-quad (4r + p) mod 8 uniform (2 lanes/quad = free).
// Counted vmcnt ladder; XCD m-chunking (mtiles % 8 == 0). Seg-fused epilogues (seg = nt>>3).
__global__ __launch_bounds__(256, 3) void gemm_v7(
    const u16* __restrict__ A, Seg s0, Seg s1, Seg s2,
    int mtiles, int ntiles) {
  const int K = 1024;
  int hwid = blockIdx.x;
  int xcd = hwid & 7, q = hwid >> 3;
  int mchunk = mtiles >> 3;
  int mt = xcd * mchunk + q / ntiles;
  int nt = q % ntiles;
  int m0 = mt * 128;
  int si = nt >> 3;
  Seg seg = (si == 0) ? s0 : (si == 1) ? s1 : s2;
  int nl0 = (nt & 7) * 128;

  int t = threadIdx.x, lane = t & 63, wv = t >> 6;
  int wr = wv >> 1, wc = wv & 1;
  int lr = lane & 15, lg = lane >> 4;

  __shared__ u16 SA[3][128 * 32];
  __shared__ u16 SB[3][128 * 32];

  // staging: thread t owns rows (t>>2), (t>>2)+64, granule t&3; source granule
  // pre-swizzled (c ^ f(row)), f(r) = (r>>1)&3; f(row+64) == f(row).
  int row0 = t >> 2, c0 = t & 3;
  int sco = (c0 ^ ((row0 >> 1) & 3)) * 8;  // u16 elems
  const u16* gA0 = A + (size_t)(m0 + row0) * K + sco;
  const u16* gB0 = seg.W + (size_t)(nl0 + row0) * K + sco;

  auto STAGE = [&](int slot, int kt) {
    __builtin_amdgcn_global_load_lds((const as1_void*)(gA0 + kt * 32),
                                     (as3_void*)(&SA[slot][0] + t * 8), 16, 0, 0);
    __builtin_amdgcn_global_load_lds((const as1_void*)(gA0 + (size_t)64 * K + kt * 32),
                                     (as3_void*)(&SA[slot][0] + 2048 + t * 8), 16, 0, 0);
    __builtin_amdgcn_global_load_lds((const as1_void*)(gB0 + kt * 32),
                                     (as3_void*)(&SB[slot][0] + t * 8), 16, 0, 0);
    __builtin_amdgcn_global_load_lds((const as1_void*)(gB0 + (size_t)64 * K + kt * 32),
                                     (as3_void*)(&SB[slot][0] + 2048 + t * 8), 16, 0, 0);
  };

  f32x4 acc[4][4] = {};

  STAGE(0, 0); STAGE(1, 1); STAGE(2, 2);
  VMCNT(8);  // slot0's 4 loads retired
  BAR();

  int slot = 0;
  const int NKT = K / 32;  // 32
#pragma unroll 1
  for (int kt = 0; kt < NKT; ++kt) {
    bf16x8 aX[4], bX[4];
#pragma unroll
    for (int m = 0; m < 4; ++m) {
      int row = wr * 64 + m * 16 + lr;
      aX[m] = *(const bf16x8*)(&SA[slot][0] + row * 32 + ((lg ^ ((row >> 1) & 3)) * 8));
    }
#pragma unroll
    for (int n = 0; n < 4; ++n) {
      int row = wc * 64 + n * 16 + lr;
      bX[n] = *(const bf16x8*)(&SB[slot][0] + row * 32 + ((lg ^ ((row >> 1) & 3)) * 8));
    }
    LGKM0();            // my reads complete (data latched in regs)
    BAR();              // all waves' reads done -> slot safe to overwrite
    if (kt + 3 < NKT) STAGE(slot, kt + 3);
    __builtin_amdgcn_s_setprio(1);
#pragma unroll
    for (int m = 0; m < 4; ++m)
#pragma unroll
      for (int n = 0; n < 4; ++n)
        acc[m][n] = __builtin_amdgcn_mfma_f32_16x16x32_bf16(aX[m], bX[n], acc[m][n], 0, 0, 0);
    __builtin_amdgcn_s_setprio(0);
    if (kt + 3 < NKT) { VMCNT(8); }        // kt+1's 4 loads (issued 2 iters ago) landed
    else if (kt + 3 == NKT) { VMCNT(4); }  // in-flight kt+1,kt+2 = 8 -> wait kt+1
    else if (kt + 2 == NKT) { VMCNT(0); }  // in-flight kt+1 = 4 -> wait all
    BAR();              // no wave laps into reading next slot early
    slot = (slot == 2) ? 0 : slot + 1;
  }

  // epilogue: per-wave 64x64, D layout col = lane&15, row = (lane>>4)*4 + r
  int rowb = m0 + wr * 64 + (lane >> 4) * 4;
#pragma unroll
  for (int m = 0; m < 4; ++m) {
#pragma unroll
    for (int n = 0; n < 4; ++n) {
      int scol = nl0 + wc * 64 + n * 16 + lr;
      float bcol = seg.bias[scol];
      int row = rowb + m * 16;
      if (seg.mode == 2) {
        // rows row..row+3 are consecutive s-positions in Vt -> one ushort4 store
        int bb = row >> seg.sk;
        int ss = row & ((1 << seg.sk) - 1);
        int h = scol >> 6, d = scol & 63;
        ushort4 o;
        o.x = f2bf(acc[m][n][0] + bcol);
        o.y = f2bf(acc[m][n][1] + bcol);
        o.z = f2bf(acc[m][n][2] + bcol);
        o.w = f2bf(acc[m][n][3] + bcol);
        *(ushort4*)(seg.outb + ((((size_t)bb * 16 + h) * 64 + d) << seg.sk) + ss) = o;
      } else if (seg.mode == 0) {
#pragma unroll
        for (int r = 0; r < 4; ++r)
          seg.outb[(size_t)(row + r) * 1024 + scol] = f2bf((acc[m][n][r] + bcol) * seg.ascale);
      } else {
#pragma unroll
        for (int r = 0; r < 4; ++r) {
          size_t idx = (size_t)(row + r) * 1024 + scol;
          seg.outf[idx] = seg.res[idx] + seg.gamma[scol] * (acc[m][n][r] + bcol);
        }
      }
    }
  }
}

// ---------------- flash attention v3: swapped QK^T 32x32, in-reg softmax, LDS K/V ----------------
// ctx written IN-PLACE over Q.
__global__ __launch_bounds__(256, 4) void attn_kernel(
    const u16* __restrict__ Q, const u16* __restrict__ Kmat,
    const u16* __restrict__ Vt, u16* __restrict__ ctx,
    int Sq, int Sk, int nq_shift) {
  int f = blockIdx.x;
  int xcd = f & 7, slot = f >> 3;
  int group = xcd * 16 + (slot >> nq_shift);
  int qt = slot & ((1 << nq_shift) - 1);
  int b = group >> 4, h = group & 15;
  int t = threadIdx.x, lane = t & 63, wv = t >> 6;
  int l31 = lane & 31, hi = lane >> 5;

  __shared__ u16 Ks[2][64 * 64];
  __shared__ u16 Vs[2][64 * 64];

  int q0 = qt * 128 + wv * 32;
  const u16* Qb = Q + (size_t)(b * Sq + q0 + l31) * 1024 + h * 64 + hi * 8;
  bf16x8 qf[4];
#pragma unroll
  for (int ds = 0; ds < 4; ++ds) qf[ds] = *(const bf16x8*)(Qb + ds * 16);

  int trow = t >> 3, tc = t & 7;
  int sc = (tc ^ (trow & 7)) * 8;
  const u16* gk = Kmat + (size_t)(b * Sk + trow) * 1024 + h * 64 + sc;
  const u16* gv = Vt + (size_t)((b * 16 + h) * 64 + trow) * Sk + sc;

  auto STAGE = [&](int buf, int kt) {
    const u16* k0 = gk + (size_t)(kt * 64) * 1024;
    const u16* v0 = gv + kt * 64;
    __builtin_amdgcn_global_load_lds((const as1_void*)k0, (as3_void*)(Ks[buf] + t * 8), 16, 0, 0);
    __builtin_amdgcn_global_load_lds((const as1_void*)(k0 + (size_t)32 * 1024), (as3_void*)(Ks[buf] + 2048 + t * 8), 16, 0, 0);
    __builtin_amdgcn_global_load_lds((const as1_void*)v0, (as3_void*)(Vs[buf] + t * 8), 16, 0, 0);
    __builtin_amdgcn_global_load_lds((const as1_void*)(v0 + (size_t)32 * Sk), (as3_void*)(Vs[buf] + 2048 + t * 8), 16, 0, 0);
  };

  STAGE(0, 0);
  __syncthreads();

  f32x16 acc0 = {}, acc1 = {};
  float m_run = -1e30f, l_run = 0.f;
  int sw = l31 & 7;

  int nt = Sk >> 6;
  for (int kt = 0; kt < nt; ++kt) {
    int cur = kt & 1;
    if (kt + 1 < nt) STAGE(cur ^ 1, kt + 1);
    const u16* kb = Ks[cur];
    f32x16 s0v = {}, s1v = {};
    __builtin_amdgcn_s_setprio(1);
#pragma unroll
    for (int ds = 0; ds < 4; ++ds) {
      int blk = 2 * ds + hi;
      bf16x8 ka0 = *(const bf16x8*)(kb + l31 * 64 + ((blk ^ sw) * 8));
      bf16x8 ka1 = *(const bf16x8*)(kb + (32 + l31) * 64 + ((blk ^ sw) * 8));
      s0v = __builtin_amdgcn_mfma_f32_32x32x16_bf16(ka0, qf[ds], s0v, 0, 0, 0);
      s1v = __builtin_amdgcn_mfma_f32_32x32x16_bf16(ka1, qf[ds], s1v, 0, 0, 0);
    }
    __builtin_amdgcn_s_setprio(0);
    float mx = s0v[0];
#pragma unroll
    for (int i = 1; i < 16; ++i) mx = fmaxf(mx, s0v[i]);
#pragma unroll
    for (int i = 0; i < 16; ++i) mx = fmaxf(mx, s1v[i]);
    mx = fmaxf(mx, __shfl_xor(mx, 32));
    if (__any(mx > m_run + 8.f)) {
      float mnew = fmaxf(m_run, mx);
      float fac = __builtin_amdgcn_exp2f(m_run - mnew);
#pragma unroll
      for (int r = 0; r < 16; ++r) {
        int src = (r & 3) + 8 * (r >> 2) + 4 * hi;
        float fr = __shfl(fac, src);
        acc0[r] *= fr;
        acc1[r] *= fr;
      }
      l_run *= fac;
      m_run = mnew;
    }
    float sum = 0.f;
#pragma unroll
    for (int i = 0; i < 16; ++i) {
      s0v[i] = __builtin_amdgcn_exp2f(s0v[i] - m_run);
      sum += s0v[i];
    }
#pragma unroll
    for (int i = 0; i < 16; ++i) {
      s1v[i] = __builtin_amdgcn_exp2f(s1v[i] - m_run);
      sum += s1v[i];
    }
    sum += __shfl_xor(sum, 32);
    l_run += sum;
    bf16x8 pa[4];
#pragma unroll
    for (int g = 0; g < 2; ++g) {
      const f32x16& s = g ? s1v : s0v;
#pragma unroll
      for (int half = 0; half < 2; ++half) {
        int o = half * 8;
        uint32_t a0, a1, b0, b1;
        asm("v_cvt_pk_bf16_f32 %0, %1, %2" : "=v"(a0) : "v"(s[o + 0]), "v"(s[o + 1]));
        asm("v_cvt_pk_bf16_f32 %0, %1, %2" : "=v"(a1) : "v"(s[o + 2]), "v"(s[o + 3]));
        asm("v_cvt_pk_bf16_f32 %0, %1, %2" : "=v"(b0) : "v"(s[o + 4]), "v"(s[o + 5]));
        asm("v_cvt_pk_bf16_f32 %0, %1, %2" : "=v"(b1) : "v"(s[o + 6]), "v"(s[o + 7]));
        asm("v_permlane32_swap_b32 %0, %1" : "+v"(a0), "+v"(b0));
        asm("v_permlane32_swap_b32 %0, %1" : "+v"(a1), "+v"(b1));
        u32x4 w;
        w[0] = a0; w[1] = a1; w[2] = b0; w[3] = b1;
        pa[g * 2 + half] = __builtin_bit_cast(bf16x8, w);
      }
    }
    const u16* vb = Vs[cur];
    __builtin_amdgcn_s_setprio(1);
#pragma unroll
    for (int ks = 0; ks < 4; ++ks) {
      int blk = 2 * ks + hi;
      bf16x8 vf0 = *(const bf16x8*)(vb + l31 * 64 + ((blk ^ sw) * 8));
      bf16x8 vf1 = *(const bf16x8*)(vb + (32 + l31) * 64 + ((blk ^ sw) * 8));
      acc0 = __builtin_amdgcn_mfma_f32_32x32x16_bf16(pa[ks], vf0, acc0, 0, 0, 0);
      acc1 = __builtin_amdgcn_mfma_f32_32x32x16_bf16(pa[ks], vf1, acc1, 0, 0, 0);
    }
    __builtin_amdgcn_s_setprio(0);
    __syncthreads();
  }
  float linv = 1.0f / l_run;
  u16* cb = ctx + (size_t)(b * Sq + q0) * 1024 + h * 64;
#pragma unroll
  for (int r = 0; r < 16; ++r) {
    int src = (r & 3) + 8 * (r >> 2) + 4 * hi;
    float li = __shfl(linv, src);
    cb[(size_t)src * 1024 + l31] = f2bf(acc0[r] * li);
    cb[(size_t)src * 1024 + 32 + l31] = f2bf(acc1[r] * li);
  }
}

extern "C" void kernel_launch(void* const* d_in, const int* in_sizes, int n_in,
                              void* d_out, int out_size, void* d_ws, size_t ws_size,
                              hipStream_t stream) {
  const float* v = (const float*)d_in[0];
  const float* l = (const float*)d_in[1];
  const float* ln_v_g = (const float*)d_in[2];
  const float* ln_v_b = (const float*)d_in[3];
  const float* ln_l_g = (const float*)d_in[4];
  const float* ln_l_b = (const float*)d_in[5];
  const float* gamma_v = (const float*)d_in[6];
  const float* gamma_l = (const float*)d_in[7];
  const float* Wf[8];
  const float* Bf[8];
  for (int i = 0; i < 8; ++i) {
    Wf[i] = (const float*)d_in[8 + 2 * i];
    Bf[i] = (const float*)d_in[9 + 2 * i];
  }
  float* v_out = (float*)d_out;
  float* l_out = v_out + (size_t)16384 * 1024;

  char* p = (char*)d_ws;
  auto alloc = [&](size_t bytes) {
    char* r = p;
    p += (bytes + 255) & ~(size_t)255;
    return r;
  };
  u16* Wbf[8];
  for (int i = 0; i < 8; ++i) Wbf[i] = (u16*)alloc((size_t)1024 * 1024 * 2);
  u16* vn   = (u16*)alloc((size_t)16384 * 1024 * 2);  // LN(v)
  u16* lnm  = (u16*)alloc((size_t)4096 * 1024 * 2);   // LN(l)
  u16* bufA = (u16*)alloc((size_t)16384 * 1024 * 2);  // Q_v2l -> ctx_v (in-place)
  u16* bufB = (u16*)alloc((size_t)4096 * 1024 * 2);   // Q_l2v -> ctx_l (in-place)
  u16* bufC = (u16*)alloc((size_t)4096 * 1024 * 2);   // Vt_v2l
  u16* bufD = (u16*)alloc((size_t)16384 * 1024 * 2);  // Vt_l2v
  u16* bufF = (u16*)alloc((size_t)4096 * 1024 * 2);   // K_v2l
  u16* bufG = (u16*)alloc((size_t)16384 * 1024 * 2);  // K_l2v

  const float QSC = 0.125f * 1.4426950408889634f;  // 1/sqrt(64) * log2(e)
  Seg zs = {};

  cvt8_kernel<<<dim3(1024, 8), 256, 0, stream>>>(
      (const float4*)Wf[0], (const float4*)Wf[1], (const float4*)Wf[2], (const float4*)Wf[3],
      (const float4*)Wf[4], (const float4*)Wf[5], (const float4*)Wf[6], (const float4*)Wf[7],
      (ushort4*)Wbf[0], (ushort4*)Wbf[1], (ushort4*)Wbf[2], (ushort4*)Wbf[3],
      (ushort4*)Wbf[4], (ushort4*)Wbf[5], (ushort4*)Wbf[6], (ushort4*)Wbf[7]);
  ln_kernel<<<16384, 256, 0, stream>>>(v, ln_v_g, ln_v_b, vn);
  ln_kernel<<<4096, 256, 0, stream>>>(l, ln_l_g, ln_l_b, lnm);

  // lnm-fused3: Q_l2v | K_v2l | Vt_v2l   (M=4096, N=3072)
  {
    Seg a = {Wbf[4], Bf[4], bufB, nullptr, nullptr, nullptr, 0, 0, QSC};
    Seg b = {Wbf[1], Bf[1], bufF, nullptr, nullptr, nullptr, 0, 0, 1.0f};
    Seg c = {Wbf[2], Bf[2], bufC, nullptr, nullptr, nullptr, 2, 9, 1.0f};
    gemm_v7<<<dim3(768), 256, 0, stream>>>(lnm, a, b, c, 32, 24);
  }
  // vn-fused3: Q_v2l | K_l2v | Vt_l2v   (M=16384, N=3072)
  {
    Seg q = {Wbf[0], Bf[0], bufA, nullptr, nullptr, nullptr, 0, 0, QSC};
    Seg k = {Wbf[5], Bf[5], bufG, nullptr, nullptr, nullptr, 0, 0, 1.0f};
    Seg vv = {Wbf[6], Bf[6], bufD, nullptr, nullptr, nullptr, 2, 11, 1.0f};
    gemm_v7<<<dim3(3072), 256, 0, stream>>>(vn, q, k, vv, 128, 24);
  }
  // attn v2l: ctx_v in-place into bufA
  attn_kernel<<<dim3(2048), 256, 0, stream>>>(bufA, bufF, bufC, bufA, 2048, 512, 4);
  // O-proj v: ctx_v @ Wo_v2l + residual
  {
    Seg o = {Wbf[3], Bf[3], nullptr, v_out, v, gamma_v, 1, 0, 1.0f};
    gemm_v7<<<dim3(1024), 256, 0, stream>>>(bufA, o, zs, zs, 128, 8);
  }
  // attn l2v: ctx_l in-place into bufB
  attn_kernel<<<dim3(512), 256, 0, stream>>>(bufB, bufG, bufD, bufB, 512, 2048, 2);
  // O-proj l
  {
    Seg o = {Wbf[7], Bf[7], nullptr, l_out, l, gamma_l, 1, 0, 1.0f};
    gemm_v7<<<dim3(256), 256, 0, stream>>>(bufB, o, zs, zs, 32, 8);
  }
}

// Round 9
// 423.022 us; speedup vs baseline: 1.2066x; 1.1337x over previous
//
#include <hip/hip_runtime.h>
#include <hip/hip_bf16.h>
#include <stdint.h>

typedef __bf16 bf16x8 __attribute__((ext_vector_type(8)));
typedef float f32x4 __attribute__((ext_vector_type(4)));
typedef float f32x16 __attribute__((ext_vector_type(16)));
typedef uint32_t u32x4 __attribute__((ext_vector_type(4)));
typedef unsigned short u16;

typedef __attribute__((address_space(1))) void as1_void;
typedef __attribute__((address_space(3))) void as3_void;

#define BAR() __builtin_amdgcn_s_barrier()
#define VMCNT(n) asm volatile("s_waitcnt vmcnt(" #n ")" ::: "memory")
#define LGKM0() asm volatile("s_waitcnt lgkmcnt(0)" ::: "memory")

__device__ __forceinline__ u16 f2bf(float f) {
  uint32_t u = __float_as_uint(f);
  u += 0x7fffu + ((u >> 16) & 1u);
  return (u16)(u >> 16);
}

// epilogue segment descriptor (uniform per block)
struct Seg {
  const u16* W;         // bf16 weight [1024,1024] (row = out col, torch W)
  const float* bias;    // [1024]
  u16* outb;            // mode 0/2 bf16 out
  float* outf;          // mode 1 fp32 out
  const float* res;     // mode 1 residual
  const float* gamma;   // mode 1 gamma
  int mode;             // 0 = bf16 rowmajor, 1 = fp32 res+gamma, 2 = Vt bf16
  int sk;               // mode2 shift
  float ascale;
};

// ---------------- fp32 -> bf16 convert (all 8 weights, one dispatch) ----------------
__global__ __launch_bounds__(256) void cvt8_kernel(
    const float4* s0, const float4* s1, const float4* s2, const float4* s3,
    const float4* s4, const float4* s5, const float4* s6, const float4* s7,
    ushort4* d0, ushort4* d1, ushort4* d2, ushort4* d3,
    ushort4* d4, ushort4* d5, ushort4* d6, ushort4* d7) {
  const float4* s; ushort4* d;
  switch (blockIdx.y) {
    case 0: s = s0; d = d0; break;
    case 1: s = s1; d = d1; break;
    case 2: s = s2; d = d2; break;
    case 3: s = s3; d = d3; break;
    case 4: s = s4; d = d4; break;
    case 5: s = s5; d = d5; break;
    case 6: s = s6; d = d6; break;
    default: s = s7; d = d7; break;
  }
  int i = blockIdx.x * 256 + threadIdx.x;
  float4 v = s[i];
  ushort4 o;
  o.x = f2bf(v.x); o.y = f2bf(v.y); o.z = f2bf(v.z); o.w = f2bf(v.w);
  d[i] = o;
}

// ---------------- layernorm fp32 -> bf16, D=1024 ----------------
__global__ __launch_bounds__(256) void ln_kernel(const float* __restrict__ x,
                                                 const float* __restrict__ g,
                                                 const float* __restrict__ b,
                                                 u16* __restrict__ out) {
  int row = blockIdx.x;
  int t = threadIdx.x;
  const float4* xr = (const float4*)(x + (size_t)row * 1024);
  float4 v = xr[t];
  float s = v.x + v.y + v.z + v.w;
  float s2 = v.x * v.x + v.y * v.y + v.z * v.z + v.w * v.w;
#pragma unroll
  for (int off = 1; off < 64; off <<= 1) {
    s += __shfl_xor(s, off);
    s2 += __shfl_xor(s2, off);
  }
  __shared__ float red[8];
  int wv = t >> 6;
  if ((t & 63) == 0) { red[wv] = s; red[4 + wv] = s2; }
  __syncthreads();
  s = red[0] + red[1] + red[2] + red[3];
  s2 = red[4] + red[5] + red[6] + red[7];
  float mu = s * (1.0f / 1024.0f);
  float var = s2 * (1.0f / 1024.0f) - mu * mu;
  float rstd = rsqrtf(var + 1e-5f);
  const float4 gv = ((const float4*)g)[t];
  const float4 bv = ((const float4*)b)[t];
  ushort4 o;
  o.x = f2bf((v.x - mu) * rstd * gv.x + bv.x);
  o.y = f2bf((v.y - mu) * rstd * gv.y + bv.y);
  o.z = f2bf((v.z - mu) * rstd * gv.z + bv.z);
  o.w = f2bf((v.w - mu) * rstd * gv.w + bv.w);
  ((ushort4*)out)[(size_t)row * 256 + t] = o;
}

// ================= gemm_v8: grouped 128x128 GEMM, single barrier per BK=32 =================
// Two trios (A, 3 segs, mtiles, ntiles); grid = mt0c*nt0c + mt1c*nt1c.
// 3-slot LDS rotation (48 KiB, 3 blocks/CU), stage kt+3 after the barrier.
// Hazards: (1) readers of slot kt%3 finish before BAR -> overwrite after BAR safe.
//          (2) VMCNT(4) before BAR: outstanding = stages kt+1,kt+2 (8 loads) ->
//              oldest 4 (stage kt+1) retired -> slot (kt+1)%3 ready for next iter.
// Swizzle key f(r) = (r>>1)&3: stored granule bank-quad (4r+p)&7 uniform (2 lanes/quad).
__global__ __launch_bounds__(256, 3) void gemm_v8(
    const u16* __restrict__ A0, Seg s00, Seg s01, Seg s02, int mt0c, int nt0c,
    const u16* __restrict__ A1, Seg s10, Seg s11, Seg s12, int mt1c, int nt1c) {
  const int K = 1024;
  int bid = blockIdx.x;
  int nb0 = mt0c * nt0c;
  const u16* A;
  Seg sa, sb, sc;
  int mtiles, ntiles, lbid;
  if (bid < nb0) {
    A = A0; mtiles = mt0c; ntiles = nt0c; lbid = bid; sa = s00; sb = s01; sc = s02;
  } else {
    A = A1; mtiles = mt1c; ntiles = nt1c; lbid = bid - nb0; sa = s10; sb = s11; sc = s12;
  }
  int xcd = lbid & 7, q = lbid >> 3;
  int mchunk = mtiles >> 3;  // requires mtiles % 8 == 0
  int mt = xcd * mchunk + q / ntiles;
  int nt = q % ntiles;
  int m0 = mt * 128;
  int si = nt >> 3;
  Seg seg = (si == 0) ? sa : (si == 1) ? sb : sc;
  int nl0 = (nt & 7) * 128;

  int t = threadIdx.x, lane = t & 63, wv = t >> 6;
  int wr = wv >> 1, wc = wv & 1;
  int lr = lane & 15, lg = lane >> 4;

  __shared__ u16 SA[3][128 * 32];
  __shared__ u16 SB[3][128 * 32];

  // staging: thread t owns rows (t>>2), (t>>2)+64, granule t&3; source granule
  // pre-swizzled (c ^ f(row)), f(r) = (r>>1)&3; f(row+64) == f(row).
  int row0 = t >> 2, c0 = t & 3;
  int sco = (c0 ^ ((row0 >> 1) & 3)) * 8;  // u16 elems
  const u16* gA0 = A + (size_t)(m0 + row0) * K + sco;
  const u16* gB0 = seg.W + (size_t)(nl0 + row0) * K + sco;

  auto STAGE = [&](int slot, int kt) {
    __builtin_amdgcn_global_load_lds((const as1_void*)(gA0 + kt * 32),
                                     (as3_void*)(&SA[slot][0] + t * 8), 16, 0, 0);
    __builtin_amdgcn_global_load_lds((const as1_void*)(gA0 + (size_t)64 * K + kt * 32),
                                     (as3_void*)(&SA[slot][0] + 2048 + t * 8), 16, 0, 0);
    __builtin_amdgcn_global_load_lds((const as1_void*)(gB0 + kt * 32),
                                     (as3_void*)(&SB[slot][0] + t * 8), 16, 0, 0);
    __builtin_amdgcn_global_load_lds((const as1_void*)(gB0 + (size_t)64 * K + kt * 32),
                                     (as3_void*)(&SB[slot][0] + 2048 + t * 8), 16, 0, 0);
  };

  f32x4 acc[4][4] = {};

  STAGE(0, 0); STAGE(1, 1); STAGE(2, 2);
  VMCNT(8);  // slot0's 4 loads retired
  BAR();

  int slot = 0;
  const int NKT = K / 32;  // 32
#pragma unroll 1
  for (int kt = 0; kt < NKT; ++kt) {
    bf16x8 aX[4], bX[4];
#pragma unroll
    for (int m = 0; m < 4; ++m) {
      int row = wr * 64 + m * 16 + lr;
      aX[m] = *(const bf16x8*)(&SA[slot][0] + row * 32 + ((lg ^ ((row >> 1) & 3)) * 8));
    }
#pragma unroll
    for (int n = 0; n < 4; ++n) {
      int row = wc * 64 + n * 16 + lr;
      bX[n] = *(const bf16x8*)(&SB[slot][0] + row * 32 + ((lg ^ ((row >> 1) & 3)) * 8));
    }
    __builtin_amdgcn_s_setprio(1);
#pragma unroll
    for (int m = 0; m < 4; ++m)
#pragma unroll
      for (int n = 0; n < 4; ++n)
        acc[m][n] = __builtin_amdgcn_mfma_f32_16x16x32_bf16(aX[m], bX[n], acc[m][n], 0, 0, 0);
    __builtin_amdgcn_s_setprio(0);
    LGKM0();                                   // all my ds_reads retired (drained by MFMA deps already)
    if (kt + 2 < NKT) { VMCNT(4); }            // stage(kt+1) retired; stage(kt+2) may fly
    else if (kt + 1 < NKT) { VMCNT(0); }       // last in-flight stage must land
    BAR();                                     // single barrier: covers both hazards
    if (kt + 3 < NKT) STAGE(slot, kt + 3);     // overwrite just-read slot
    slot = (slot == 2) ? 0 : slot + 1;
  }

  // epilogue: per-wave 64x64, D layout col = lane&15, row = (lane>>4)*4 + r
  int rowb = m0 + wr * 64 + (lane >> 4) * 4;
#pragma unroll
  for (int m = 0; m < 4; ++m) {
#pragma unroll
    for (int n = 0; n < 4; ++n) {
      int scol = nl0 + wc * 64 + n * 16 + lr;
      float bcol = seg.bias[scol];
      int row = rowb + m * 16;
      if (seg.mode == 2) {
        int bb = row >> seg.sk;
        int ss = row & ((1 << seg.sk) - 1);
        int h = scol >> 6, d = scol & 63;
        ushort4 o;
        o.x = f2bf(acc[m][n][0] + bcol);
        o.y = f2bf(acc[m][n][1] + bcol);
        o.z = f2bf(acc[m][n][2] + bcol);
        o.w = f2bf(acc[m][n][3] + bcol);
        *(ushort4*)(seg.outb + ((((size_t)bb * 16 + h) * 64 + d) << seg.sk) + ss) = o;
      } else if (seg.mode == 0) {
#pragma unroll
        for (int r = 0; r < 4; ++r)
          seg.outb[(size_t)(row + r) * 1024 + scol] = f2bf((acc[m][n][r] + bcol) * seg.ascale);
      } else {
#pragma unroll
        for (int r = 0; r < 4; ++r) {
          size_t idx = (size_t)(row + r) * 1024 + scol;
          seg.outf[idx] = seg.res[idx] + seg.gamma[scol] * (acc[m][n][r] + bcol);
        }
      }
    }
  }
}

// ---------------- merged flash attention: v2l blocks [0, nb0), l2v blocks [nb0, ...) ----------------
// Swapped QK^T 32x32, in-reg softmax, LDS K/V double-buffer. ctx written IN-PLACE over Q.
__global__ __launch_bounds__(256, 4) void attn2_kernel(
    const u16* __restrict__ Q0, const u16* __restrict__ K0,
    const u16* __restrict__ V0, u16* __restrict__ C0, int Sq0, int Sk0, int nqs0, int nb0,
    const u16* __restrict__ Q1, const u16* __restrict__ K1,
    const u16* __restrict__ V1, u16* __restrict__ C1, int Sq1, int Sk1, int nqs1) {
  int bid = blockIdx.x;
  const u16 *Q, *Kmat, *Vt;
  u16* ctx;
  int Sq, Sk, nq_shift, f;
  if (bid < nb0) {
    Q = Q0; Kmat = K0; Vt = V0; ctx = C0; Sq = Sq0; Sk = Sk0; nq_shift = nqs0; f = bid;
  } else {
    Q = Q1; Kmat = K1; Vt = V1; ctx = C1; Sq = Sq1; Sk = Sk1; nq_shift = nqs1; f = bid - nb0;
  }
  int xcd = f & 7, slot = f >> 3;
  int group = xcd * 16 + (slot >> nq_shift);
  int qt = slot & ((1 << nq_shift) - 1);
  int b = group >> 4, h = group & 15;
  int t = threadIdx.x, lane = t & 63, wv = t >> 6;
  int l31 = lane & 31, hi = lane >> 5;

  __shared__ u16 Ks[2][64 * 64];
  __shared__ u16 Vs[2][64 * 64];

  int q0 = qt * 128 + wv * 32;
  const u16* Qb = Q + (size_t)(b * Sq + q0 + l31) * 1024 + h * 64 + hi * 8;
  bf16x8 qf[4];
#pragma unroll
  for (int ds = 0; ds < 4; ++ds) qf[ds] = *(const bf16x8*)(Qb + ds * 16);

  int trow = t >> 3, tc = t & 7;
  int sc = (tc ^ (trow & 7)) * 8;
  const u16* gk = Kmat + (size_t)(b * Sk + trow) * 1024 + h * 64 + sc;
  const u16* gv = Vt + (size_t)((b * 16 + h) * 64 + trow) * Sk + sc;

  auto STAGE = [&](int buf, int kt) {
    const u16* k0 = gk + (size_t)(kt * 64) * 1024;
    const u16* v0 = gv + kt * 64;
    __builtin_amdgcn_global_load_lds((const as1_void*)k0, (as3_void*)(Ks[buf] + t * 8), 16, 0, 0);
    __builtin_amdgcn_global_load_lds((const as1_void*)(k0 + (size_t)32 * 1024), (as3_void*)(Ks[buf] + 2048 + t * 8), 16, 0, 0);
    __builtin_amdgcn_global_load_lds((const as1_void*)v0, (as3_void*)(Vs[buf] + t * 8), 16, 0, 0);
    __builtin_amdgcn_global_load_lds((const as1_void*)(v0 + (size_t)32 * Sk), (as3_void*)(Vs[buf] + 2048 + t * 8), 16, 0, 0);
  };

  STAGE(0, 0);
  __syncthreads();

  f32x16 acc0 = {}, acc1 = {};
  float m_run = -1e30f, l_run = 0.f;
  int sw = l31 & 7;

  int nt = Sk >> 6;
  for (int kt = 0; kt < nt; ++kt) {
    int cur = kt & 1;
    if (kt + 1 < nt) STAGE(cur ^ 1, kt + 1);
    const u16* kb = Ks[cur];
    f32x16 s0v = {}, s1v = {};
    __builtin_amdgcn_s_setprio(1);
#pragma unroll
    for (int ds = 0; ds < 4; ++ds) {
      int blk = 2 * ds + hi;
      bf16x8 ka0 = *(const bf16x8*)(kb + l31 * 64 + ((blk ^ sw) * 8));
      bf16x8 ka1 = *(const bf16x8*)(kb + (32 + l31) * 64 + ((blk ^ sw) * 8));
      s0v = __builtin_amdgcn_mfma_f32_32x32x16_bf16(ka0, qf[ds], s0v, 0, 0, 0);
      s1v = __builtin_amdgcn_mfma_f32_32x32x16_bf16(ka1, qf[ds], s1v, 0, 0, 0);
    }
    __builtin_amdgcn_s_setprio(0);
    float mx = s0v[0];
#pragma unroll
    for (int i = 1; i < 16; ++i) mx = fmaxf(mx, s0v[i]);
#pragma unroll
    for (int i = 0; i < 16; ++i) mx = fmaxf(mx, s1v[i]);
    mx = fmaxf(mx, __shfl_xor(mx, 32));
    if (__any(mx > m_run + 8.f)) {
      float mnew = fmaxf(m_run, mx);
      float fac = __builtin_amdgcn_exp2f(m_run - mnew);
#pragma unroll
      for (int r = 0; r < 16; ++r) {
        int src = (r & 3) + 8 * (r >> 2) + 4 * hi;
        float fr = __shfl(fac, src);
        acc0[r] *= fr;
        acc1[r] *= fr;
      }
      l_run *= fac;
      m_run = mnew;
    }
    float sum = 0.f;
#pragma unroll
    for (int i = 0; i < 16; ++i) {
      s0v[i] = __builtin_amdgcn_exp2f(s0v[i] - m_run);
      sum += s0v[i];
    }
#pragma unroll
    for (int i = 0; i < 16; ++i) {
      s1v[i] = __builtin_amdgcn_exp2f(s1v[i] - m_run);
      sum += s1v[i];
    }
    sum += __shfl_xor(sum, 32);
    l_run += sum;
    bf16x8 pa[4];
#pragma unroll
    for (int g = 0; g < 2; ++g) {
      const f32x16& s = g ? s1v : s0v;
#pragma unroll
      for (int half = 0; half < 2; ++half) {
        int o = half * 8;
        uint32_t a0, a1, b0, b1;
        asm("v_cvt_pk_bf16_f32 %0, %1, %2" : "=v"(a0) : "v"(s[o + 0]), "v"(s[o + 1]));
        asm("v_cvt_pk_bf16_f32 %0, %1, %2" : "=v"(a1) : "v"(s[o + 2]), "v"(s[o + 3]));
        asm("v_cvt_pk_bf16_f32 %0, %1, %2" : "=v"(b0) : "v"(s[o + 4]), "v"(s[o + 5]));
        asm("v_cvt_pk_bf16_f32 %0, %1, %2" : "=v"(b1) : "v"(s[o + 6]), "v"(s[o + 7]));
        asm("v_permlane32_swap_b32 %0, %1" : "+v"(a0), "+v"(b0));
        asm("v_permlane32_swap_b32 %0, %1" : "+v"(a1), "+v"(b1));
        u32x4 w;
        w[0] = a0; w[1] = a1; w[2] = b0; w[3] = b1;
        pa[g * 2 + half] = __builtin_bit_cast(bf16x8, w);
      }
    }
    const u16* vb = Vs[cur];
    __builtin_amdgcn_s_setprio(1);
#pragma unroll
    for (int ks = 0; ks < 4; ++ks) {
      int blk = 2 * ks + hi;
      bf16x8 vf0 = *(const bf16x8*)(vb + l31 * 64 + ((blk ^ sw) * 8));
      bf16x8 vf1 = *(const bf16x8*)(vb + (32 + l31) * 64 + ((blk ^ sw) * 8));
      acc0 = __builtin_amdgcn_mfma_f32_32x32x16_bf16(pa[ks], vf0, acc0, 0, 0, 0);
      acc1 = __builtin_amdgcn_mfma_f32_32x32x16_bf16(pa[ks], vf1, acc1, 0, 0, 0);
    }
    __builtin_amdgcn_s_setprio(0);
    __syncthreads();
  }
  float linv = 1.0f / l_run;
  u16* cb = ctx + (size_t)(b * Sq + q0) * 1024 + h * 64;
#pragma unroll
  for (int r = 0; r < 16; ++r) {
    int src = (r & 3) + 8 * (r >> 2) + 4 * hi;
    float li = __shfl(linv, src);
    cb[(size_t)src * 1024 + l31] = f2bf(acc0[r] * li);
    cb[(size_t)src * 1024 + 32 + l31] = f2bf(acc1[r] * li);
  }
}

extern "C" void kernel_launch(void* const* d_in, const int* in_sizes, int n_in,
                              void* d_out, int out_size, void* d_ws, size_t ws_size,
                              hipStream_t stream) {
  const float* v = (const float*)d_in[0];
  const float* l = (const float*)d_in[1];
  const float* ln_v_g = (const float*)d_in[2];
  const float* ln_v_b = (const float*)d_in[3];
  const float* ln_l_g = (const float*)d_in[4];
  const float* ln_l_b = (const float*)d_in[5];
  const float* gamma_v = (const float*)d_in[6];
  const float* gamma_l = (const float*)d_in[7];
  const float* Wf[8];
  const float* Bf[8];
  for (int i = 0; i < 8; ++i) {
    Wf[i] = (const float*)d_in[8 + 2 * i];
    Bf[i] = (const float*)d_in[9 + 2 * i];
  }
  float* v_out = (float*)d_out;
  float* l_out = v_out + (size_t)16384 * 1024;

  char* p = (char*)d_ws;
  auto alloc = [&](size_t bytes) {
    char* r = p;
    p += (bytes + 255) & ~(size_t)255;
    return r;
  };
  u16* Wbf[8];
  for (int i = 0; i < 8; ++i) Wbf[i] = (u16*)alloc((size_t)1024 * 1024 * 2);
  u16* vn   = (u16*)alloc((size_t)16384 * 1024 * 2);  // LN(v)
  u16* lnm  = (u16*)alloc((size_t)4096 * 1024 * 2);   // LN(l)
  u16* bufA = (u16*)alloc((size_t)16384 * 1024 * 2);  // Q_v2l -> ctx_v (in-place)
  u16* bufB = (u16*)alloc((size_t)4096 * 1024 * 2);   // Q_l2v -> ctx_l (in-place)
  u16* bufC = (u16*)alloc((size_t)4096 * 1024 * 2);   // Vt_v2l
  u16* bufD = (u16*)alloc((size_t)16384 * 1024 * 2);  // Vt_l2v
  u16* bufF = (u16*)alloc((size_t)4096 * 1024 * 2);   // K_v2l
  u16* bufG = (u16*)alloc((size_t)16384 * 1024 * 2);  // K_l2v

  const float QSC = 0.125f * 1.4426950408889634f;  // 1/sqrt(64) * log2(e)
  Seg zs = {};

  cvt8_kernel<<<dim3(1024, 8), 256, 0, stream>>>(
      (const float4*)Wf[0], (const float4*)Wf[1], (const float4*)Wf[2], (const float4*)Wf[3],
      (const float4*)Wf[4], (const float4*)Wf[5], (const float4*)Wf[6], (const float4*)Wf[7],
      (ushort4*)Wbf[0], (ushort4*)Wbf[1], (ushort4*)Wbf[2], (ushort4*)Wbf[3],
      (ushort4*)Wbf[4], (ushort4*)Wbf[5], (ushort4*)Wbf[6], (ushort4*)Wbf[7]);
  ln_kernel<<<16384, 256, 0, stream>>>(v, ln_v_g, ln_v_b, vn);
  ln_kernel<<<4096, 256, 0, stream>>>(l, ln_l_g, ln_l_b, lnm);

  // grouped GEMM #1: trio0 on lnm (Q_l2v | K_v2l | Vt_v2l), trio1 on vn (Q_v2l | K_l2v | Vt_l2v)
  {
    Seg a = {Wbf[4], Bf[4], bufB, nullptr, nullptr, nullptr, 0, 0, QSC};
    Seg b = {Wbf[1], Bf[1], bufF, nullptr, nullptr, nullptr, 0, 0, 1.0f};
    Seg c = {Wbf[2], Bf[2], bufC, nullptr, nullptr, nullptr, 2, 9, 1.0f};
    Seg q = {Wbf[0], Bf[0], bufA, nullptr, nullptr, nullptr, 0, 0, QSC};
    Seg k = {Wbf[5], Bf[5], bufG, nullptr, nullptr, nullptr, 0, 0, 1.0f};
    Seg vv = {Wbf[6], Bf[6], bufD, nullptr, nullptr, nullptr, 2, 11, 1.0f};
    gemm_v8<<<dim3(768 + 3072), 256, 0, stream>>>(lnm, a, b, c, 32, 24,
                                                  vn, q, k, vv, 128, 24);
  }
  // merged attention: v2l (2048 blocks) + l2v (512 blocks), ctx in-place over Q
  attn2_kernel<<<dim3(2048 + 512), 256, 0, stream>>>(
      bufA, bufF, bufC, bufA, 2048, 512, 4, 2048,
      bufB, bufG, bufD, bufB, 512, 2048, 2);
  // grouped GEMM #2: O-proj v (ctx_v) + O-proj l (ctx_l), fused residual epilogues
  {
    Seg ov = {Wbf[3], Bf[3], nullptr, v_out, v, gamma_v, 1, 0, 1.0f};
    Seg ol = {Wbf[7], Bf[7], nullptr, l_out, l, gamma_l, 1, 0, 1.0f};
    gemm_v8<<<dim3(1024 + 256), 256, 0, stream>>>(bufA, ov, zs, zs, 128, 8,
                                                  bufB, ol, zs, zs, 32, 8);
  }
}